// Round 13
// baseline (137.603 us; speedup 1.0000x reference)
//
#include <hip/hip_runtime.h>
#include <hip/hip_bf16.h>
#include <cstdint>

#define D_   256
#define E_   4096
#define NN_  2048

typedef float f32x4_t __attribute__((ext_vector_type(4)));
typedef short bf16x8_t __attribute__((ext_vector_type(8)));
typedef short bf16x4_t __attribute__((ext_vector_type(4)));

__device__ inline short f2bf(float f) {
    union { float fv; unsigned u; } v; v.fv = f;
    unsigned r = v.u + 0x7fffu + ((v.u >> 16) & 1u);
    return (short)(r >> 16);
}

__device__ inline unsigned cvtpk_bf16(float lo, float hi) {
    unsigned r;
    asm("v_cvt_pk_bf16_f32 %0, %1, %2" : "=v"(r) : "v"(lo), "v"(hi));
    return r;
}

// ---------------------------------------------------------------------------
// bf16 MFMA GEMM (validated r7/r8/r10): C = epi(A @ Bm^T + bias), 64x64 tile,
// 4 waves, BK=32, dbuf LDS, 1 barrier per K-step.
// ABF16: A is bf16 (direct 16B staging, no cvt). OUT: 0=f32 C, 1=bf16 C
// (cols<256 scaled by qsc), 2=qkv split (cols<512 -> qkvb bf16 w/ q-scale;
// cols 512.. -> vt[head][d][key] bf16 transposed V). SCATTER: f32 atomicAdd
// via ei1. HASADD: += addsrc (f32, exact). ACT: LeakyReLU(0.2).
// ---------------------------------------------------------------------------
template<int ACT, bool GATHER, bool SCATTER, bool HASADD, bool ABF16, int OUT>
__global__ __launch_bounds__(256)
void mgemm_k(const void* __restrict__ A, const float* __restrict__ Bm,
             const float* __restrict__ bias, const float* __restrict__ addsrc,
             void* __restrict__ C, short* __restrict__ vtb,
             int M, int N, int K,
             const int* __restrict__ ei0, const int* __restrict__ ei1,
             const float* __restrict__ x, const float* __restrict__ eattr,
             float qsc)
{
    __shared__ char lds[16384];
    const int tid = threadIdx.x;
    const int w = tid >> 6, l = tid & 63;
    const int g = l >> 4, ln = l & 15;
    const int wr = w >> 1, wc = w & 1;
    const int m0 = blockIdx.x * 64, n0 = blockIdx.y * 64;

    const int srow = tid >> 2;
    const int sck  = (tid & 3) * 8;
    const int sswz = (srow & 7) << 4;
    int gi1 = 0, gi0 = 0;
    if (GATHER) { gi1 = ei1[m0 + srow]; gi0 = ei0[m0 + srow]; }

    f32x4_t acc[2][2];
    #pragma unroll
    for (int m = 0; m < 2; m++)
        #pragma unroll
        for (int n = 0; n < 2; n++)
            acc[m][n] = f32x4_t{0.f, 0.f, 0.f, 0.f};

    const int nt = K >> 5;
    float4 ga0, ga1, gb0, gb1;
    bf16x8_t gab;

    auto loadG = [&](int kk) {
        const int cb = kk + sck;
        if (ABF16) {
            gab = *(const bf16x8_t*)((const short*)A + (size_t)(m0 + srow) * K + cb);
        } else {
            const float* src;
            if (GATHER) {
                if (cb < 256)      src = x + (size_t)gi1 * 256 + cb;
                else if (cb < 512) src = x + (size_t)gi0 * 256 + (cb - 256);
                else               src = eattr + (size_t)(m0 + srow) * 256 + (cb - 512);
            } else {
                src = (const float*)A + (size_t)(m0 + srow) * K + cb;
            }
            ga0 = *(const float4*)src;
            ga1 = *(const float4*)(src + 4);
        }
        const float* bsrc = Bm + (size_t)(n0 + srow) * K + cb;
        gb0 = *(const float4*)bsrc;
        gb1 = *(const float4*)(bsrc + 4);
    };
    auto writeS = [&](int buf) {
        const int off = (srow*64 + sck*2) ^ sswz;
        if (ABF16) {
            *(bf16x8_t*)(lds + buf*4096 + off) = gab;
        } else {
            uint4 pa;
            pa.x = cvtpk_bf16(ga0.x, ga0.y); pa.y = cvtpk_bf16(ga0.z, ga0.w);
            pa.z = cvtpk_bf16(ga1.x, ga1.y); pa.w = cvtpk_bf16(ga1.z, ga1.w);
            *(uint4*)(lds + buf*4096 + off) = pa;
        }
        uint4 pb;
        pb.x = cvtpk_bf16(gb0.x, gb0.y); pb.y = cvtpk_bf16(gb0.z, gb0.w);
        pb.z = cvtpk_bf16(gb1.x, gb1.y); pb.w = cvtpk_bf16(gb1.z, gb1.w);
        *(uint4*)(lds + 8192 + buf*4096 + off) = pb;
    };

    loadG(0);
    writeS(0);
    __syncthreads();
    int cur = 0;
    for (int t = 0; t < nt; ++t) {
        if (t + 1 < nt) loadG((t + 1) << 5);
        bf16x8_t af[2], bfr[2];
        #pragma unroll
        for (int m = 0; m < 2; m++) {
            const int row = wr*32 + m*16 + ln;
            af[m] = *(const bf16x8_t*)(lds + cur*4096 + ((row*64 + g*16) ^ ((row&7)<<4)));
        }
        #pragma unroll
        for (int n = 0; n < 2; n++) {
            const int row = wc*32 + n*16 + ln;
            bfr[n] = *(const bf16x8_t*)(lds + 8192 + cur*4096 + ((row*64 + g*16) ^ ((row&7)<<4)));
        }
        #pragma unroll
        for (int m = 0; m < 2; m++)
            #pragma unroll
            for (int n = 0; n < 2; n++)
                acc[m][n] = __builtin_amdgcn_mfma_f32_16x16x32_bf16(af[m], bfr[n], acc[m][n], 0, 0, 0);
        if (t + 1 < nt) writeS(cur ^ 1);
        __syncthreads();
        cur ^= 1;
    }

    #pragma unroll
    for (int m = 0; m < 2; m++) {
        #pragma unroll
        for (int n = 0; n < 2; n++) {
            const int col = n0 + wc*32 + n*16 + ln;
            const float bv = bias[col];
            const int row0 = m0 + wr*32 + m*16 + g*4;
            float pv[4];
            #pragma unroll
            for (int r = 0; r < 4; r++) {
                float v = acc[m][n][r] + bv;
                if (ACT == 1) v = v > 0.f ? v : 0.2f * v;
                if (HASADD) v += addsrc[(size_t)(row0 + r) * N + col];
                pv[r] = v;
            }
            if (SCATTER) {
                #pragma unroll
                for (int r = 0; r < 4; r++)
                    atomicAdd(&((float*)C)[(size_t)ei1[row0 + r] * 256 + col], pv[r]);
            } else if (OUT == 0) {
                #pragma unroll
                for (int r = 0; r < 4; r++)
                    ((float*)C)[(size_t)(row0 + r) * N + col] = pv[r];
            } else if (OUT == 1) {
                #pragma unroll
                for (int r = 0; r < 4; r++)
                    ((short*)C)[(size_t)(row0 + r) * N + col] =
                        f2bf((col < 256) ? pv[r] * qsc : pv[r]);
            } else {   // OUT == 2: qkv split
                if (col < 512) {
                    #pragma unroll
                    for (int r = 0; r < 4; r++)
                        ((short*)C)[(size_t)(row0 + r) * 768 + col] =
                            f2bf((col < 256) ? pv[r] * qsc : pv[r]);
                } else {
                    const int hd = (col - 512) >> 5, d = (col - 512) & 31;
                    bf16x4_t pk;
                    #pragma unroll
                    for (int r = 0; r < 4; r++) pk[r] = f2bf(pv[r]);
                    *(bf16x4_t*)(vtb + (size_t)hd*131072 + (size_t)d*4096 + row0) = pk;
                }
            }
        }
    }
}

// ---------------------------------------------------------------------------
// Prep: mask bit-pack (int32 0/1 layout, established r1->r2 A/B) + aggr zero
// + root transpose, one kernel. Blocks 0..2047: pack+zero; 2048..2063: rootT.
// ---------------------------------------------------------------------------
__global__ __launch_bounds__(256)
void prep_k(const int* __restrict__ mraw, unsigned int* __restrict__ pm,
            const float* __restrict__ root, float* __restrict__ rootT,
            float* __restrict__ aggr)
{
    __shared__ float T[64][65];
    const int bid = blockIdx.x;
    if (bid < 2048) {
        const int t = bid * 256 + threadIdx.x;
        aggr[t] = 0.f;
        const int row = t >> 7, wb = t & 127;
        unsigned int bits = 0;
        const uint4* p = (const uint4*)(mraw + (size_t)row * 4096 + wb * 32);
        #pragma unroll
        for (int g = 0; g < 8; g++) {
            const uint4 v = p[g];
            if (v.x) bits |= 1u << (g*4+0);
            if (v.y) bits |= 1u << (g*4+1);
            if (v.z) bits |= 1u << (g*4+2);
            if (v.w) bits |= 1u << (g*4+3);
        }
        pm[t] = bits;
    } else {
        const int bt = bid - 2048;
        const int m0 = (bt >> 2) * 64, n0 = (bt & 3) * 64;
        const int r = threadIdx.x >> 6, c = threadIdx.x & 63;
        #pragma unroll
        for (int i = 0; i < 16; i++)
            T[r + i*4][c] = root[(size_t)(m0 + r + i*4) * 256 + n0 + c];
        __syncthreads();
        #pragma unroll
        for (int i = 0; i < 16; i++)
            rootT[(size_t)(n0 + r + i*4) * 256 + m0 + c] = T[c][r + i*4];
    }
}

// ---------------------------------------------------------------------------
// MFMA bf16 flash attention (r8 structure + setprio + mask prefetch,
// validated 55.0 us, FETCH 18.5 MB). Swapped QK^T; FIXED-SHIFT softmax in
// base-2: q pre-scaled by log2e/sqrt(32) in S3, p = exp2(s' - 12*log2e)
// == exp(s_orig - 12) exactly; saves the v_mul inside every __expf.
// In-block split-K x2 strided; dbuf K/V; additive merge.
// DO NOT widen split-K: x4 (r9) and range-split (r5) collapsed L2.
// ---------------------------------------------------------------------------
__global__ __launch_bounds__(512, 4)
void attn_k(const short* __restrict__ qkvb, const short* __restrict__ vt,
            const unsigned int* __restrict__ pmask, float* __restrict__ o)
{
    __shared__ char lds[49152];
    const int tid = threadIdx.x;
    const int w2 = tid >> 6, l = tid & 63;
    const int g = l >> 4, ln = l & 15;
    const int gi = w2 >> 2, wq = w2 & 3;
    const int head = blockIdx.x >> 6;
    const int q0 = (blockIdx.x & 63) * 64;
    const int qa = q0 + wq * 16 + ln;

    const bf16x8_t qf = *(const bf16x8_t*)(qkvb + (size_t)qa*768 + head*32 + g*8);

    f32x4_t oT0 = {0.f,0.f,0.f,0.f};
    f32x4_t oT1 = {0.f,0.f,0.f,0.f};
    float lsum = 0.f;

    const int st = tid & 255;
    const int skey = st >> 2, sc = st & 3;
    const int sd = st >> 3, skc = st & 7;
    const short* kgp = qkvb + 256 + head*32 + sc*8;
    const short* vgp = vt + (size_t)head*131072 + (size_t)sd*4096 + skc*8;
    char* Kg = lds + gi*8192;
    char* Vg = lds + 16384 + gi*8192;
    char* Pw = lds + 32768 + w2*2048;
    const unsigned int* mrow = pmask + (size_t)qa*128;
    const int kswz = (skey & 7) << 4, vswz = (sd & 7) << 4;
    const int pswz = (ln & 7) << 4;

    uint2 mwc;
    {   // stage this group's first tile (tt = gi) -> buf 0; preload its mask
        const int k0 = gi * 64;
        const bf16x8_t kv = *(const bf16x8_t*)(kgp + (size_t)(k0 + skey)*768);
        *(bf16x8_t*)(Kg + ((skey*64 + sc*16) ^ kswz)) = kv;
        const bf16x8_t vv = *(const bf16x8_t*)(vgp + k0);
        *(bf16x8_t*)(Vg + ((sd*128 + skc*16) ^ vswz)) = vv;
        mwc = *(const uint2*)(mrow + gi*2);
    }

    for (int i = 0; i < 32; ++i) {
        __syncthreads();
        const int cur = i & 1;
        const int tt = 2*i + gi;
        uint2 mwn;
        if (i < 31) {   // prefetch this group's next tile (tt+2) + its mask
            const int k0n = (tt + 2) * 64;
            const bf16x8_t kv = *(const bf16x8_t*)(kgp + (size_t)(k0n + skey)*768);
            *(bf16x8_t*)(Kg + (cur^1)*4096 + ((skey*64 + sc*16) ^ kswz)) = kv;
            const bf16x8_t vv = *(const bf16x8_t*)(vgp + k0n);
            *(bf16x8_t*)(Vg + (cur^1)*4096 + ((sd*128 + skc*16) ^ vswz)) = vv;
            mwn = *(const uint2*)(mrow + (tt + 2)*2);
        }
        char* Kb = Kg + cur*4096;
        char* Vb = Vg + cur*4096;

        // S^T = mfma(K, Q): col=q=ln, rows = keys kt*16+g*4+r
        f32x4_t s[4];
        __builtin_amdgcn_s_setprio(1);
        #pragma unroll
        for (int kt = 0; kt < 4; kt++) {
            const int key = kt*16 + ln;
            const bf16x8_t kf = *(const bf16x8_t*)(Kb + ((key*64 + g*16) ^ ((key & 7) << 4)));
            f32x4_t z = {0.f,0.f,0.f,0.f};
            s[kt] = __builtin_amdgcn_mfma_f32_16x16x32_bf16(kf, qf, z, 0, 0, 0);
        }
        __builtin_amdgcn_s_setprio(0);

        // fixed-shift masked exp2; lsum; pack P -> LDS
        #pragma unroll
        for (int kt = 0; kt < 4; kt++) {
            const unsigned word = (kt < 2) ? mwc.x : mwc.y;
            float p[4];
            #pragma unroll
            for (int r = 0; r < 4; r++) {
                const float e = exp2f(s[kt][r] - 17.312340490667562f);  // 12*log2e
                p[r] = ((word >> ((kt & 1)*16 + g*4 + r)) & 1u) ? e : 0.f;
            }
            lsum += (p[0] + p[1]) + (p[2] + p[3]);
            uint2 pk;
            pk.x = cvtpk_bf16(p[0], p[1]);
            pk.y = cvtpk_bf16(p[2], p[3]);
            *(uint2*)(Pw + ((ln*128 + kt*32 + g*8) ^ pswz)) = pk;
        }

        // PV: O^T += Vt . P
        __builtin_amdgcn_s_setprio(1);
        #pragma unroll
        for (int kh = 0; kh < 2; kh++) {
            const bf16x8_t pf = *(const bf16x8_t*)(Pw + ((ln*128 + kh*64 + g*16) ^ pswz));
            const bf16x8_t vf0 = *(const bf16x8_t*)(Vb + ((ln*128 + kh*64 + g*16) ^ pswz));
            const bf16x8_t vf1 = *(const bf16x8_t*)(Vb + (((16+ln)*128 + kh*64 + g*16) ^ pswz));
            oT0 = __builtin_amdgcn_mfma_f32_16x16x32_bf16(vf0, pf, oT0, 0, 0, 0);
            oT1 = __builtin_amdgcn_mfma_f32_16x16x32_bf16(vf1, pf, oT1, 0, 0, 0);
        }
        __builtin_amdgcn_s_setprio(0);
        mwc = mwn;
    }

    // ---- additive merge of the two key-group partials ----
    __syncthreads();
    *(f32x4_t*)(lds + w2*2048 + l*32)      = oT0;
    *(f32x4_t*)(lds + w2*2048 + l*32 + 16) = oT1;
    ((float*)(lds + 16384))[w2*64 + l] = lsum;
    __syncthreads();
    if (gi == 0) {
        const int pw = w2 + 4;
        const f32x4_t b0 = *(const f32x4_t*)(lds + pw*2048 + l*32);
        const f32x4_t b1 = *(const f32x4_t*)(lds + pw*2048 + l*32 + 16);
        const float lp = ((const float*)(lds + 16384))[pw*64 + l];
        oT0 += b0; oT1 += b1;
        lsum += lp;
        lsum += __shfl_xor(lsum, 16);
        lsum += __shfl_xor(lsum, 32);
        const float inv = 1.0f / fmaxf(lsum, 1e-37f);
        float* op = o + (size_t)qa * 256 + head*32;
        float4 v0 = {oT0[0]*inv, oT0[1]*inv, oT0[2]*inv, oT0[3]*inv};
        float4 v1 = {oT1[0]*inv, oT1[1]*inv, oT1[2]*inv, oT1[3]*inv};
        *(float4*)(op + g*4) = v0;
        *(float4*)(op + 16 + g*4) = v1;
    }
}

// ---------------------------------------------------------------------------
// LayerNorm over 256 dims, one block per row.
// ---------------------------------------------------------------------------
__global__ __launch_bounds__(256)
void ln_k(const float* __restrict__ in, const float* __restrict__ g,
          const float* __restrict__ b, float* __restrict__ out)
{
    const int n = blockIdx.x, t = threadIdx.x;
    const float v = in[(size_t)n * 256 + t];
    float s1 = v, s2 = v * v;
    #pragma unroll
    for (int off = 32; off > 0; off >>= 1) {
        s1 += __shfl_xor(s1, off);
        s2 += __shfl_xor(s2, off);
    }
    __shared__ float r1[4], r2[4];
    const int wv = t >> 6;
    if ((t & 63) == 0) { r1[wv] = s1; r2[wv] = s2; }
    __syncthreads();
    const float t1 = r1[0] + r1[1] + r1[2] + r1[3];
    const float t2 = r2[0] + r2[1] + r2[2] + r2[3];
    const float mu  = t1 * (1.0f / 256.0f);
    const float var = t2 * (1.0f / 256.0f) - mu * mu;
    const float rs  = rsqrtf(var + 1e-5f);
    out[(size_t)n * 256 + t] = (v - mu) * rs * g[t] + b[t];
}

// ---------------------------------------------------------------------------
extern "C" void kernel_launch(void* const* d_in, const int* in_sizes, int n_in,
                              void* d_out, int out_size, void* d_ws, size_t ws_size,
                              hipStream_t stream)
{
    const float* x     = (const float*)d_in[0];
    const int*   ei    = (const int*)  d_in[1];
    const float* eattr = (const float*)d_in[2];
    const int*   mask  = (const int*)  d_in[3];
    const float* W1   = (const float*)d_in[4];
    const float* b1   = (const float*)d_in[5];
    const float* W2   = (const float*)d_in[6];
    const float* b2   = (const float*)d_in[7];
    const float* ipw  = (const float*)d_in[8];
    const float* ipb  = (const float*)d_in[9];
    const float* ow   = (const float*)d_in[10];
    const float* ob   = (const float*)d_in[11];
    const float* root = (const float*)d_in[12];
    const float* bp   = (const float*)d_in[13];
    const float* ln1g = (const float*)d_in[14];
    const float* ln1b = (const float*)d_in[15];
    const float* ln2g = (const float*)d_in[16];
    const float* ln2b = (const float*)d_in[17];
    const float* linw = (const float*)d_in[18];
    const float* linb = (const float*)d_in[19];
    const int* ei0 = ei;
    const int* ei1 = ei + E_;

    float* ws = (float*)d_ws;
    short* h1b   = (short*)ws;                      // [E,256] bf16
    short* hb    = (short*)(ws + 524288);           // [E,256] bf16
    float* o     = ws + 1048576;                    // [E,256] f32 (attn out)
    float* y1    = ws + 1048576;                    //   reuse: o dead after S5
    float* z     = ws + 1572864;                    //   reuse: o dead after S5
    short* qkvb  = (short*)(ws + 2097152);          // [E,768] bf16 (q pre-scaled)
    float* aggr  = ws + 3670016;                    // [N,256] f32
    float* outb  = ws + 4194304;                    // [N,256] f32
    unsigned int* pmask = (unsigned int*)(ws + 4718592);  // [4096][128] bits
    short* vt    = (short*)(ws + 5242896);          // [8][32][4096] bf16
    float* rootT = ws + 5767184;                    // [256][256] f32

    // NOTE: y1/z overlay o's region — o is dead after S5 (LN1/F2 run later).

    dim3 blk(256);
    // prep: mask bits + aggr zero + rootT
    prep_k<<<dim3(2064), blk, 0, stream>>>(mask, pmask, root, rootT, aggr);

    // S1: h1b = bf16(leakyrelu(cat(x_i,x_j,eattr) @ W1^T + b1))   [MFMA]
    mgemm_k<1,true,false,false,false,1><<<dim3(64,4), blk, 0, stream>>>(
        nullptr, W1, b1, nullptr, h1b, nullptr, E_, 256, 768, ei0, ei1, x, eattr, 1.0f);
    // S2: hb = bf16(h1b @ W2^T + b2)   [MFMA, bf16 A]
    mgemm_k<0,false,false,false,true,1><<<dim3(64,4), blk, 0, stream>>>(
        h1b, W2, b2, nullptr, hb, nullptr, E_, 256, 256, nullptr, nullptr, nullptr, nullptr, 1.0f);
    // S3: qkvb + vt = hb @ in_proj_w^T + b; q scaled by log2e/sqrt(32);
    //     V columns written transposed into vt (vtrans folded in)
    mgemm_k<0,false,false,false,true,2><<<dim3(64,12), blk, 0, stream>>>(
        hb, ipw, ipb, nullptr, qkvb, vt, E_, 768, 256, nullptr, nullptr, nullptr, nullptr,
        0.25503486f);   // log2(e)/sqrt(32)
    // S4: MFMA flash attention -> o (f32)
    attn_k<<<dim3(512), dim3(512), 0, stream>>>(qkvb, vt, pmask, o);
    // S5: msg = o @ out_w^T + out_b, scatter-add to aggr   [MFMA]
    mgemm_k<0,false,true,false,false,0><<<dim3(64,4), blk, 0, stream>>>(
        o, ow, ob, nullptr, aggr, nullptr, E_, 256, 256, nullptr, ei1, nullptr, nullptr, 1.0f);
    // S6: outb = x @ root + aggr + bias_p   [MFMA + exact f32 add]
    mgemm_k<0,false,false,true,false,0><<<dim3(32,4), blk, 0, stream>>>(
        x, rootT, bp, aggr, outb, nullptr, NN_, 256, 256, nullptr, nullptr, nullptr, nullptr, 1.0f);
    // LN1
    ln_k<<<dim3(2048), blk, 0, stream>>>(outb, ln1g, ln1b, y1);
    // F2: z = y1 + y1 @ lin_w^T + lin_b   [MFMA + exact f32 residual]
    mgemm_k<0,false,false,true,false,0><<<dim3(32,4), blk, 0, stream>>>(
        y1, linw, linb, y1, z, nullptr, NN_, 256, 256, nullptr, nullptr, nullptr, nullptr, 1.0f);
    // LN2 -> out
    ln_k<<<dim3(2048), blk, 0, stream>>>(z, ln2g, ln2b, (float*)d_out);
}

// Round 14
// 122.212 us; speedup vs baseline: 1.1259x; 1.1259x over previous
//
#include <hip/hip_runtime.h>
#include <hip/hip_bf16.h>
#include <cstdint>

#define D_   256
#define E_   4096
#define NN_  2048

typedef float f32x4_t __attribute__((ext_vector_type(4)));
typedef short bf16x8_t __attribute__((ext_vector_type(8)));
typedef short bf16x4_t __attribute__((ext_vector_type(4)));

__device__ inline short f2bf(float f) {
    union { float fv; unsigned u; } v; v.fv = f;
    unsigned r = v.u + 0x7fffu + ((v.u >> 16) & 1u);
    return (short)(r >> 16);
}

__device__ inline unsigned cvtpk_bf16(float lo, float hi) {
    unsigned r;
    asm("v_cvt_pk_bf16_f32 %0, %1, %2" : "=v"(r) : "v"(lo), "v"(hi));
    return r;
}

// Raw hardware exp2: v_exp_f32 computes 2^x in one transcendental op.
// (exp2f() is the PRECISE OCML call — costs ~15us/attn, r13 lesson.)
__device__ inline float hw_exp2(float x) {
    float r;
    asm("v_exp_f32 %0, %1" : "=v"(r) : "v"(x));
    return r;
}

// ---------------------------------------------------------------------------
// bf16 MFMA GEMM (validated r7/r8/r10): C = epi(A @ Bm^T + bias), 64x64 tile,
// 4 waves, BK=32, dbuf LDS, 1 barrier per K-step.
// ABF16: A is bf16 (direct 16B staging, no cvt). OUT: 0=f32 C, 1=bf16 C
// (cols<256 scaled by qsc), 2=qkv split (cols<512 -> qkvb bf16 w/ q-scale;
// cols 512.. -> vt[head][d][key] bf16 transposed V). SCATTER: f32 atomicAdd
// via ei1. HASADD: += addsrc (f32, exact). ACT: LeakyReLU(0.2).
// ---------------------------------------------------------------------------
template<int ACT, bool GATHER, bool SCATTER, bool HASADD, bool ABF16, int OUT>
__global__ __launch_bounds__(256)
void mgemm_k(const void* __restrict__ A, const float* __restrict__ Bm,
             const float* __restrict__ bias, const float* __restrict__ addsrc,
             void* __restrict__ C, short* __restrict__ vtb,
             int M, int N, int K,
             const int* __restrict__ ei0, const int* __restrict__ ei1,
             const float* __restrict__ x, const float* __restrict__ eattr,
             float qsc)
{
    __shared__ char lds[16384];
    const int tid = threadIdx.x;
    const int w = tid >> 6, l = tid & 63;
    const int g = l >> 4, ln = l & 15;
    const int wr = w >> 1, wc = w & 1;
    const int m0 = blockIdx.x * 64, n0 = blockIdx.y * 64;

    const int srow = tid >> 2;
    const int sck  = (tid & 3) * 8;
    const int sswz = (srow & 7) << 4;
    int gi1 = 0, gi0 = 0;
    if (GATHER) { gi1 = ei1[m0 + srow]; gi0 = ei0[m0 + srow]; }

    f32x4_t acc[2][2];
    #pragma unroll
    for (int m = 0; m < 2; m++)
        #pragma unroll
        for (int n = 0; n < 2; n++)
            acc[m][n] = f32x4_t{0.f, 0.f, 0.f, 0.f};

    const int nt = K >> 5;
    float4 ga0, ga1, gb0, gb1;
    bf16x8_t gab;

    auto loadG = [&](int kk) {
        const int cb = kk + sck;
        if (ABF16) {
            gab = *(const bf16x8_t*)((const short*)A + (size_t)(m0 + srow) * K + cb);
        } else {
            const float* src;
            if (GATHER) {
                if (cb < 256)      src = x + (size_t)gi1 * 256 + cb;
                else if (cb < 512) src = x + (size_t)gi0 * 256 + (cb - 256);
                else               src = eattr + (size_t)(m0 + srow) * 256 + (cb - 512);
            } else {
                src = (const float*)A + (size_t)(m0 + srow) * K + cb;
            }
            ga0 = *(const float4*)src;
            ga1 = *(const float4*)(src + 4);
        }
        const float* bsrc = Bm + (size_t)(n0 + srow) * K + cb;
        gb0 = *(const float4*)bsrc;
        gb1 = *(const float4*)(bsrc + 4);
    };
    auto writeS = [&](int buf) {
        const int off = (srow*64 + sck*2) ^ sswz;
        if (ABF16) {
            *(bf16x8_t*)(lds + buf*4096 + off) = gab;
        } else {
            uint4 pa;
            pa.x = cvtpk_bf16(ga0.x, ga0.y); pa.y = cvtpk_bf16(ga0.z, ga0.w);
            pa.z = cvtpk_bf16(ga1.x, ga1.y); pa.w = cvtpk_bf16(ga1.z, ga1.w);
            *(uint4*)(lds + buf*4096 + off) = pa;
        }
        uint4 pb;
        pb.x = cvtpk_bf16(gb0.x, gb0.y); pb.y = cvtpk_bf16(gb0.z, gb0.w);
        pb.z = cvtpk_bf16(gb1.x, gb1.y); pb.w = cvtpk_bf16(gb1.z, gb1.w);
        *(uint4*)(lds + 8192 + buf*4096 + off) = pb;
    };

    loadG(0);
    writeS(0);
    __syncthreads();
    int cur = 0;
    for (int t = 0; t < nt; ++t) {
        if (t + 1 < nt) loadG((t + 1) << 5);
        bf16x8_t af[2], bfr[2];
        #pragma unroll
        for (int m = 0; m < 2; m++) {
            const int row = wr*32 + m*16 + ln;
            af[m] = *(const bf16x8_t*)(lds + cur*4096 + ((row*64 + g*16) ^ ((row&7)<<4)));
        }
        #pragma unroll
        for (int n = 0; n < 2; n++) {
            const int row = wc*32 + n*16 + ln;
            bfr[n] = *(const bf16x8_t*)(lds + 8192 + cur*4096 + ((row*64 + g*16) ^ ((row&7)<<4)));
        }
        #pragma unroll
        for (int m = 0; m < 2; m++)
            #pragma unroll
            for (int n = 0; n < 2; n++)
                acc[m][n] = __builtin_amdgcn_mfma_f32_16x16x32_bf16(af[m], bfr[n], acc[m][n], 0, 0, 0);
        if (t + 1 < nt) writeS(cur ^ 1);
        __syncthreads();
        cur ^= 1;
    }

    #pragma unroll
    for (int m = 0; m < 2; m++) {
        #pragma unroll
        for (int n = 0; n < 2; n++) {
            const int col = n0 + wc*32 + n*16 + ln;
            const float bv = bias[col];
            const int row0 = m0 + wr*32 + m*16 + g*4;
            float pv[4];
            #pragma unroll
            for (int r = 0; r < 4; r++) {
                float v = acc[m][n][r] + bv;
                if (ACT == 1) v = v > 0.f ? v : 0.2f * v;
                if (HASADD) v += addsrc[(size_t)(row0 + r) * N + col];
                pv[r] = v;
            }
            if (SCATTER) {
                #pragma unroll
                for (int r = 0; r < 4; r++)
                    atomicAdd(&((float*)C)[(size_t)ei1[row0 + r] * 256 + col], pv[r]);
            } else if (OUT == 0) {
                #pragma unroll
                for (int r = 0; r < 4; r++)
                    ((float*)C)[(size_t)(row0 + r) * N + col] = pv[r];
            } else if (OUT == 1) {
                #pragma unroll
                for (int r = 0; r < 4; r++)
                    ((short*)C)[(size_t)(row0 + r) * N + col] =
                        f2bf((col < 256) ? pv[r] * qsc : pv[r]);
            } else {   // OUT == 2: qkv split
                if (col < 512) {
                    #pragma unroll
                    for (int r = 0; r < 4; r++)
                        ((short*)C)[(size_t)(row0 + r) * 768 + col] =
                            f2bf((col < 256) ? pv[r] * qsc : pv[r]);
                } else {
                    const int hd = (col - 512) >> 5, d = (col - 512) & 31;
                    bf16x4_t pk;
                    #pragma unroll
                    for (int r = 0; r < 4; r++) pk[r] = f2bf(pv[r]);
                    *(bf16x4_t*)(vtb + (size_t)hd*131072 + (size_t)d*4096 + row0) = pk;
                }
            }
        }
    }
}

// ---------------------------------------------------------------------------
// Prep: mask bit-pack (int32 0/1 layout, established r1->r2 A/B) + aggr zero
// + root transpose, one kernel. Blocks 0..2047: pack+zero; 2048..2063: rootT.
// ---------------------------------------------------------------------------
__global__ __launch_bounds__(256)
void prep_k(const int* __restrict__ mraw, unsigned int* __restrict__ pm,
            const float* __restrict__ root, float* __restrict__ rootT,
            float* __restrict__ aggr)
{
    __shared__ float T[64][65];
    const int bid = blockIdx.x;
    if (bid < 2048) {
        const int t = bid * 256 + threadIdx.x;
        aggr[t] = 0.f;
        const int row = t >> 7, wb = t & 127;
        unsigned int bits = 0;
        const uint4* p = (const uint4*)(mraw + (size_t)row * 4096 + wb * 32);
        #pragma unroll
        for (int g = 0; g < 8; g++) {
            const uint4 v = p[g];
            if (v.x) bits |= 1u << (g*4+0);
            if (v.y) bits |= 1u << (g*4+1);
            if (v.z) bits |= 1u << (g*4+2);
            if (v.w) bits |= 1u << (g*4+3);
        }
        pm[t] = bits;
    } else {
        const int bt = bid - 2048;
        const int m0 = (bt >> 2) * 64, n0 = (bt & 3) * 64;
        const int r = threadIdx.x >> 6, c = threadIdx.x & 63;
        #pragma unroll
        for (int i = 0; i < 16; i++)
            T[r + i*4][c] = root[(size_t)(m0 + r + i*4) * 256 + n0 + c];
        __syncthreads();
        #pragma unroll
        for (int i = 0; i < 16; i++)
            rootT[(size_t)(n0 + r + i*4) * 256 + m0 + c] = T[c][r + i*4];
    }
}

// ---------------------------------------------------------------------------
// MFMA bf16 flash attention (r8 structure + setprio + mask prefetch).
// Swapped QK^T; fixed-shift softmax in base-2: q pre-scaled by
// log2e/sqrt(32) in S3, p = hw_exp2(s' - 12*log2e) == exp(s_orig - 12)
// exactly — hw_exp2 is raw v_exp_f32 (single transcendental; plain exp2f
// is the precise OCML libm call, +15us — r13 lesson).
// In-block split-K x2 strided; dbuf K/V; additive merge.
// DO NOT widen split-K: x4 (r9) and range-split (r5) collapsed L2.
// ---------------------------------------------------------------------------
__global__ __launch_bounds__(512, 4)
void attn_k(const short* __restrict__ qkvb, const short* __restrict__ vt,
            const unsigned int* __restrict__ pmask, float* __restrict__ o)
{
    __shared__ char lds[49152];
    const int tid = threadIdx.x;
    const int w2 = tid >> 6, l = tid & 63;
    const int g = l >> 4, ln = l & 15;
    const int gi = w2 >> 2, wq = w2 & 3;
    const int head = blockIdx.x >> 6;
    const int q0 = (blockIdx.x & 63) * 64;
    const int qa = q0 + wq * 16 + ln;

    const bf16x8_t qf = *(const bf16x8_t*)(qkvb + (size_t)qa*768 + head*32 + g*8);

    f32x4_t oT0 = {0.f,0.f,0.f,0.f};
    f32x4_t oT1 = {0.f,0.f,0.f,0.f};
    float lsum = 0.f;

    const int st = tid & 255;
    const int skey = st >> 2, sc = st & 3;
    const int sd = st >> 3, skc = st & 7;
    const short* kgp = qkvb + 256 + head*32 + sc*8;
    const short* vgp = vt + (size_t)head*131072 + (size_t)sd*4096 + skc*8;
    char* Kg = lds + gi*8192;
    char* Vg = lds + 16384 + gi*8192;
    char* Pw = lds + 32768 + w2*2048;
    const unsigned int* mrow = pmask + (size_t)qa*128;
    const int kswz = (skey & 7) << 4, vswz = (sd & 7) << 4;
    const int pswz = (ln & 7) << 4;

    uint2 mwc;
    {   // stage this group's first tile (tt = gi) -> buf 0; preload its mask
        const int k0 = gi * 64;
        const bf16x8_t kv = *(const bf16x8_t*)(kgp + (size_t)(k0 + skey)*768);
        *(bf16x8_t*)(Kg + ((skey*64 + sc*16) ^ kswz)) = kv;
        const bf16x8_t vv = *(const bf16x8_t*)(vgp + k0);
        *(bf16x8_t*)(Vg + ((sd*128 + skc*16) ^ vswz)) = vv;
        mwc = *(const uint2*)(mrow + gi*2);
    }

    for (int i = 0; i < 32; ++i) {
        __syncthreads();
        const int cur = i & 1;
        const int tt = 2*i + gi;
        uint2 mwn;
        if (i < 31) {   // prefetch this group's next tile (tt+2) + its mask
            const int k0n = (tt + 2) * 64;
            const bf16x8_t kv = *(const bf16x8_t*)(kgp + (size_t)(k0n + skey)*768);
            *(bf16x8_t*)(Kg + (cur^1)*4096 + ((skey*64 + sc*16) ^ kswz)) = kv;
            const bf16x8_t vv = *(const bf16x8_t*)(vgp + k0n);
            *(bf16x8_t*)(Vg + (cur^1)*4096 + ((sd*128 + skc*16) ^ vswz)) = vv;
            mwn = *(const uint2*)(mrow + (tt + 2)*2);
        }
        char* Kb = Kg + cur*4096;
        char* Vb = Vg + cur*4096;

        // S^T = mfma(K, Q): col=q=ln, rows = keys kt*16+g*4+r
        f32x4_t s[4];
        __builtin_amdgcn_s_setprio(1);
        #pragma unroll
        for (int kt = 0; kt < 4; kt++) {
            const int key = kt*16 + ln;
            const bf16x8_t kf = *(const bf16x8_t*)(Kb + ((key*64 + g*16) ^ ((key & 7) << 4)));
            f32x4_t z = {0.f,0.f,0.f,0.f};
            s[kt] = __builtin_amdgcn_mfma_f32_16x16x32_bf16(kf, qf, z, 0, 0, 0);
        }
        __builtin_amdgcn_s_setprio(0);

        // fixed-shift masked exp2 (raw v_exp_f32); lsum; pack P -> LDS
        #pragma unroll
        for (int kt = 0; kt < 4; kt++) {
            const unsigned word = (kt < 2) ? mwc.x : mwc.y;
            float p[4];
            #pragma unroll
            for (int r = 0; r < 4; r++) {
                const float e = hw_exp2(s[kt][r] - 17.312340490667562f);  // 12*log2e
                p[r] = ((word >> ((kt & 1)*16 + g*4 + r)) & 1u) ? e : 0.f;
            }
            lsum += (p[0] + p[1]) + (p[2] + p[3]);
            uint2 pk;
            pk.x = cvtpk_bf16(p[0], p[1]);
            pk.y = cvtpk_bf16(p[2], p[3]);
            *(uint2*)(Pw + ((ln*128 + kt*32 + g*8) ^ pswz)) = pk;
        }

        // PV: O^T += Vt . P
        __builtin_amdgcn_s_setprio(1);
        #pragma unroll
        for (int kh = 0; kh < 2; kh++) {
            const bf16x8_t pf = *(const bf16x8_t*)(Pw + ((ln*128 + kh*64 + g*16) ^ pswz));
            const bf16x8_t vf0 = *(const bf16x8_t*)(Vb + ((ln*128 + kh*64 + g*16) ^ pswz));
            const bf16x8_t vf1 = *(const bf16x8_t*)(Vb + (((16+ln)*128 + kh*64 + g*16) ^ pswz));
            oT0 = __builtin_amdgcn_mfma_f32_16x16x32_bf16(vf0, pf, oT0, 0, 0, 0);
            oT1 = __builtin_amdgcn_mfma_f32_16x16x32_bf16(vf1, pf, oT1, 0, 0, 0);
        }
        __builtin_amdgcn_s_setprio(0);
        mwc = mwn;
    }

    // ---- additive merge of the two key-group partials ----
    __syncthreads();
    *(f32x4_t*)(lds + w2*2048 + l*32)      = oT0;
    *(f32x4_t*)(lds + w2*2048 + l*32 + 16) = oT1;
    ((float*)(lds + 16384))[w2*64 + l] = lsum;
    __syncthreads();
    if (gi == 0) {
        const int pw = w2 + 4;
        const f32x4_t b0 = *(const f32x4_t*)(lds + pw*2048 + l*32);
        const f32x4_t b1 = *(const f32x4_t*)(lds + pw*2048 + l*32 + 16);
        const float lp = ((const float*)(lds + 16384))[pw*64 + l];
        oT0 += b0; oT1 += b1;
        lsum += lp;
        lsum += __shfl_xor(lsum, 16);
        lsum += __shfl_xor(lsum, 32);
        const float inv = 1.0f / fmaxf(lsum, 1e-37f);
        float* op = o + (size_t)qa * 256 + head*32;
        float4 v0 = {oT0[0]*inv, oT0[1]*inv, oT0[2]*inv, oT0[3]*inv};
        float4 v1 = {oT1[0]*inv, oT1[1]*inv, oT1[2]*inv, oT1[3]*inv};
        *(float4*)(op + g*4) = v0;
        *(float4*)(op + 16 + g*4) = v1;
    }
}

// ---------------------------------------------------------------------------
// LayerNorm over 256 dims, one block per row.
// ---------------------------------------------------------------------------
__global__ __launch_bounds__(256)
void ln_k(const float* __restrict__ in, const float* __restrict__ g,
          const float* __restrict__ b, float* __restrict__ out)
{
    const int n = blockIdx.x, t = threadIdx.x;
    const float v = in[(size_t)n * 256 + t];
    float s1 = v, s2 = v * v;
    #pragma unroll
    for (int off = 32; off > 0; off >>= 1) {
        s1 += __shfl_xor(s1, off);
        s2 += __shfl_xor(s2, off);
    }
    __shared__ float r1[4], r2[4];
    const int wv = t >> 6;
    if ((t & 63) == 0) { r1[wv] = s1; r2[wv] = s2; }
    __syncthreads();
    const float t1 = r1[0] + r1[1] + r1[2] + r1[3];
    const float t2 = r2[0] + r2[1] + r2[2] + r2[3];
    const float mu  = t1 * (1.0f / 256.0f);
    const float var = t2 * (1.0f / 256.0f) - mu * mu;
    const float rs  = rsqrtf(var + 1e-5f);
    out[(size_t)n * 256 + t] = (v - mu) * rs * g[t] + b[t];
}

// ---------------------------------------------------------------------------
extern "C" void kernel_launch(void* const* d_in, const int* in_sizes, int n_in,
                              void* d_out, int out_size, void* d_ws, size_t ws_size,
                              hipStream_t stream)
{
    const float* x     = (const float*)d_in[0];
    const int*   ei    = (const int*)  d_in[1];
    const float* eattr = (const float*)d_in[2];
    const int*   mask  = (const int*)  d_in[3];
    const float* W1   = (const float*)d_in[4];
    const float* b1   = (const float*)d_in[5];
    const float* W2   = (const float*)d_in[6];
    const float* b2   = (const float*)d_in[7];
    const float* ipw  = (const float*)d_in[8];
    const float* ipb  = (const float*)d_in[9];
    const float* ow   = (const float*)d_in[10];
    const float* ob   = (const float*)d_in[11];
    const float* root = (const float*)d_in[12];
    const float* bp   = (const float*)d_in[13];
    const float* ln1g = (const float*)d_in[14];
    const float* ln1b = (const float*)d_in[15];
    const float* ln2g = (const float*)d_in[16];
    const float* ln2b = (const float*)d_in[17];
    const float* linw = (const float*)d_in[18];
    const float* linb = (const float*)d_in[19];
    const int* ei0 = ei;
    const int* ei1 = ei + E_;

    float* ws = (float*)d_ws;
    short* h1b   = (short*)ws;                      // [E,256] bf16
    short* hb    = (short*)(ws + 524288);           // [E,256] bf16
    float* o     = ws + 1048576;                    // [E,256] f32 (attn out)
    float* y1    = ws + 1048576;                    //   reuse: o dead after S5
    float* z     = ws + 1572864;                    //   reuse: o dead after S5
    short* qkvb  = (short*)(ws + 2097152);          // [E,768] bf16 (q pre-scaled)
    float* aggr  = ws + 3670016;                    // [N,256] f32
    float* outb  = ws + 4194304;                    // [N,256] f32
    unsigned int* pmask = (unsigned int*)(ws + 4718592);  // [4096][128] bits
    short* vt    = (short*)(ws + 5242896);          // [8][32][4096] bf16
    float* rootT = ws + 5767184;                    // [256][256] f32

    dim3 blk(256);
    // prep: mask bits + aggr zero + rootT
    prep_k<<<dim3(2064), blk, 0, stream>>>(mask, pmask, root, rootT, aggr);

    // S1: h1b = bf16(leakyrelu(cat(x_i,x_j,eattr) @ W1^T + b1))   [MFMA]
    mgemm_k<1,true,false,false,false,1><<<dim3(64,4), blk, 0, stream>>>(
        nullptr, W1, b1, nullptr, h1b, nullptr, E_, 256, 768, ei0, ei1, x, eattr, 1.0f);
    // S2: hb = bf16(h1b @ W2^T + b2)   [MFMA, bf16 A]
    mgemm_k<0,false,false,false,true,1><<<dim3(64,4), blk, 0, stream>>>(
        h1b, W2, b2, nullptr, hb, nullptr, E_, 256, 256, nullptr, nullptr, nullptr, nullptr, 1.0f);
    // S3: qkvb + vt = hb @ in_proj_w^T + b; q scaled by log2e/sqrt(32);
    //     V columns written transposed into vt (vtrans folded in)
    mgemm_k<0,false,false,false,true,2><<<dim3(64,12), blk, 0, stream>>>(
        hb, ipw, ipb, nullptr, qkvb, vt, E_, 768, 256, nullptr, nullptr, nullptr, nullptr,
        0.25503486f);   // log2(e)/sqrt(32)
    // S4: MFMA flash attention -> o (f32)
    attn_k<<<dim3(512), dim3(512), 0, stream>>>(qkvb, vt, pmask, o);
    // S5: msg = o @ out_w^T + out_b, scatter-add to aggr   [MFMA]
    mgemm_k<0,false,true,false,false,0><<<dim3(64,4), blk, 0, stream>>>(
        o, ow, ob, nullptr, aggr, nullptr, E_, 256, 256, nullptr, ei1, nullptr, nullptr, 1.0f);
    // S6: outb = x @ root + aggr + bias_p   [MFMA + exact f32 add]
    mgemm_k<0,false,false,true,false,0><<<dim3(32,4), blk, 0, stream>>>(
        x, rootT, bp, aggr, outb, nullptr, NN_, 256, 256, nullptr, nullptr, nullptr, nullptr, 1.0f);
    // LN1
    ln_k<<<dim3(2048), blk, 0, stream>>>(outb, ln1g, ln1b, y1);
    // F2: z = y1 + y1 @ lin_w^T + lin_b   [MFMA + exact f32 residual]
    mgemm_k<0,false,false,true,false,0><<<dim3(32,4), blk, 0, stream>>>(
        y1, linw, linb, y1, z, nullptr, NN_, 256, 256, nullptr, nullptr, nullptr, nullptr, 1.0f);
    // LN2 -> out
    ln_k<<<dim3(2048), blk, 0, stream>>>(z, ln2g, ln2b, (float*)d_out);
}

// Round 15
// 116.386 us; speedup vs baseline: 1.1823x; 1.0500x over previous
//
#include <hip/hip_runtime.h>
#include <hip/hip_bf16.h>
#include <cstdint>

#define D_   256
#define E_   4096
#define NN_  2048

typedef float f32x4_t __attribute__((ext_vector_type(4)));
typedef short bf16x8_t __attribute__((ext_vector_type(8)));
typedef short bf16x4_t __attribute__((ext_vector_type(4)));

__device__ inline short f2bf(float f) {
    union { float fv; unsigned u; } v; v.fv = f;
    unsigned r = v.u + 0x7fffu + ((v.u >> 16) & 1u);
    return (short)(r >> 16);
}

__device__ inline unsigned cvtpk_bf16(float lo, float hi) {
    unsigned r;
    asm("v_cvt_pk_bf16_f32 %0, %1, %2" : "=v"(r) : "v"(lo), "v"(hi));
    return r;
}

// Raw hardware exp2: v_exp_f32 computes 2^x in one transcendental op.
// (exp2f() is the PRECISE OCML call — cost ~15us/attn, r13 lesson.)
__device__ inline float hw_exp2(float x) {
    float r;
    asm("v_exp_f32 %0, %1" : "=v"(r) : "v"(x));
    return r;
}

// ---------------------------------------------------------------------------
// bf16 MFMA GEMM, BK=64 (r15): C = epi(A @ Bm^T + bias), 64x64 tile, 4 waves,
// dbuf LDS (2x(8KB A + 8KB B) = 32KB), 1 barrier per K-step, 8 MFMA/wave/step.
// BK=64 halves barriers vs r14's BK=32 (m132 lesson: BK=128/64KB LDS is the
// occupancy cliff; 32KB keeps ~5 blocks/CU).
// ABF16: A is bf16 (direct 16B staging). OUT: 0=f32 C, 1=bf16 C (cols<256
// scaled by qsc), 2=qkv split (cols<512 -> qkvb; cols 512.. -> vt transposed).
// SCATTER: f32 atomicAdd via ei1. HASADD: += addsrc (f32, exact).
// ---------------------------------------------------------------------------
template<int ACT, bool GATHER, bool SCATTER, bool HASADD, bool ABF16, int OUT>
__global__ __launch_bounds__(256)
void mgemm_k(const void* __restrict__ A, const float* __restrict__ Bm,
             const float* __restrict__ bias, const float* __restrict__ addsrc,
             void* __restrict__ C, short* __restrict__ vtb,
             int M, int N, int K,
             const int* __restrict__ ei0, const int* __restrict__ ei1,
             const float* __restrict__ x, const float* __restrict__ eattr,
             float qsc)
{
    __shared__ char lds[32768];   // A dbuf 2x8KB @0, B dbuf 2x8KB @16384
    const int tid = threadIdx.x;
    const int w = tid >> 6, l = tid & 63;
    const int g = l >> 4, ln = l & 15;
    const int wr = w >> 1, wc = w & 1;
    const int m0 = blockIdx.x * 64, n0 = blockIdx.y * 64;

    const int srow = tid >> 2;          // staging row 0..63
    const int sck  = (tid & 3) * 16;    // staging col chunk (16 elements)
    const int sswz = (srow & 7) << 4;
    int gi1 = 0, gi0 = 0;
    if (GATHER) { gi1 = ei1[m0 + srow]; gi0 = ei0[m0 + srow]; }

    f32x4_t acc[2][2];
    #pragma unroll
    for (int m = 0; m < 2; m++)
        #pragma unroll
        for (int n = 0; n < 2; n++)
            acc[m][n] = f32x4_t{0.f, 0.f, 0.f, 0.f};

    const int nt = K >> 6;
    float4 ga[4], gb[4];
    bf16x8_t gab[2];

    auto loadG = [&](int kk) {
        const int cb = kk + sck;   // multiple of 16: never straddles gather regions
        if (ABF16) {
            const short* as = (const short*)A + (size_t)(m0 + srow) * K + cb;
            gab[0] = *(const bf16x8_t*)as;
            gab[1] = *(const bf16x8_t*)(as + 8);
        } else {
            const float* src;
            if (GATHER) {
                if (cb < 256)      src = x + (size_t)gi1 * 256 + cb;
                else if (cb < 512) src = x + (size_t)gi0 * 256 + (cb - 256);
                else               src = eattr + (size_t)(m0 + srow) * 256 + (cb - 512);
            } else {
                src = (const float*)A + (size_t)(m0 + srow) * K + cb;
            }
            #pragma unroll
            for (int q = 0; q < 4; q++) ga[q] = *(const float4*)(src + q*4);
        }
        const float* bsrc = Bm + (size_t)(n0 + srow) * K + cb;
        #pragma unroll
        for (int q = 0; q < 4; q++) gb[q] = *(const float4*)(bsrc + q*4);
    };
    auto writeS = [&](int buf) {
        const int base = srow*128 + sck*2;
        const int off0 = base ^ sswz;
        const int off1 = (base + 16) ^ sswz;   // swizzle applied per-address
        if (ABF16) {
            *(bf16x8_t*)(lds + buf*8192 + off0) = gab[0];
            *(bf16x8_t*)(lds + buf*8192 + off1) = gab[1];
        } else {
            uint4 p0, p1;
            p0.x = cvtpk_bf16(ga[0].x, ga[0].y); p0.y = cvtpk_bf16(ga[0].z, ga[0].w);
            p0.z = cvtpk_bf16(ga[1].x, ga[1].y); p0.w = cvtpk_bf16(ga[1].z, ga[1].w);
            p1.x = cvtpk_bf16(ga[2].x, ga[2].y); p1.y = cvtpk_bf16(ga[2].z, ga[2].w);
            p1.z = cvtpk_bf16(ga[3].x, ga[3].y); p1.w = cvtpk_bf16(ga[3].z, ga[3].w);
            *(uint4*)(lds + buf*8192 + off0) = p0;
            *(uint4*)(lds + buf*8192 + off1) = p1;
        }
        uint4 q0, q1;
        q0.x = cvtpk_bf16(gb[0].x, gb[0].y); q0.y = cvtpk_bf16(gb[0].z, gb[0].w);
        q0.z = cvtpk_bf16(gb[1].x, gb[1].y); q0.w = cvtpk_bf16(gb[1].z, gb[1].w);
        q1.x = cvtpk_bf16(gb[2].x, gb[2].y); q1.y = cvtpk_bf16(gb[2].z, gb[2].w);
        q1.z = cvtpk_bf16(gb[3].x, gb[3].y); q1.w = cvtpk_bf16(gb[3].z, gb[3].w);
        *(uint4*)(lds + 16384 + buf*8192 + off0) = q0;
        *(uint4*)(lds + 16384 + buf*8192 + off1) = q1;
    };

    loadG(0);
    writeS(0);
    __syncthreads();
    int cur = 0;
    for (int t = 0; t < nt; ++t) {
        if (t + 1 < nt) loadG((t + 1) << 6);
        #pragma unroll
        for (int kc = 0; kc < 2; kc++) {
            bf16x8_t af[2], bfr[2];
            #pragma unroll
            for (int m = 0; m < 2; m++) {
                const int row = wr*32 + m*16 + ln;
                af[m] = *(const bf16x8_t*)(lds + cur*8192 +
                        ((row*128 + kc*64 + g*16) ^ ((row&7)<<4)));
            }
            #pragma unroll
            for (int n = 0; n < 2; n++) {
                const int row = wc*32 + n*16 + ln;
                bfr[n] = *(const bf16x8_t*)(lds + 16384 + cur*8192 +
                         ((row*128 + kc*64 + g*16) ^ ((row&7)<<4)));
            }
            #pragma unroll
            for (int m = 0; m < 2; m++)
                #pragma unroll
                for (int n = 0; n < 2; n++)
                    acc[m][n] = __builtin_amdgcn_mfma_f32_16x16x32_bf16(af[m], bfr[n], acc[m][n], 0, 0, 0);
        }
        if (t + 1 < nt) writeS(cur ^ 1);
        __syncthreads();
        cur ^= 1;
    }

    #pragma unroll
    for (int m = 0; m < 2; m++) {
        #pragma unroll
        for (int n = 0; n < 2; n++) {
            const int col = n0 + wc*32 + n*16 + ln;
            const float bv = bias[col];
            const int row0 = m0 + wr*32 + m*16 + g*4;
            float pv[4];
            #pragma unroll
            for (int r = 0; r < 4; r++) {
                float v = acc[m][n][r] + bv;
                if (ACT == 1) v = v > 0.f ? v : 0.2f * v;
                if (HASADD) v += addsrc[(size_t)(row0 + r) * N + col];
                pv[r] = v;
            }
            if (SCATTER) {
                #pragma unroll
                for (int r = 0; r < 4; r++)
                    atomicAdd(&((float*)C)[(size_t)ei1[row0 + r] * 256 + col], pv[r]);
            } else if (OUT == 0) {
                #pragma unroll
                for (int r = 0; r < 4; r++)
                    ((float*)C)[(size_t)(row0 + r) * N + col] = pv[r];
            } else if (OUT == 1) {
                #pragma unroll
                for (int r = 0; r < 4; r++)
                    ((short*)C)[(size_t)(row0 + r) * N + col] =
                        f2bf((col < 256) ? pv[r] * qsc : pv[r]);
            } else {   // OUT == 2: qkv split
                if (col < 512) {
                    #pragma unroll
                    for (int r = 0; r < 4; r++)
                        ((short*)C)[(size_t)(row0 + r) * 768 + col] =
                            f2bf((col < 256) ? pv[r] * qsc : pv[r]);
                } else {
                    const int hd = (col - 512) >> 5, d = (col - 512) & 31;
                    bf16x4_t pk;
                    #pragma unroll
                    for (int r = 0; r < 4; r++) pk[r] = f2bf(pv[r]);
                    *(bf16x4_t*)(vtb + (size_t)hd*131072 + (size_t)d*4096 + row0) = pk;
                }
            }
        }
    }
}

// ---------------------------------------------------------------------------
// Prep: mask bit-pack (int32 0/1 layout, established r1->r2 A/B) + aggr zero
// + root transpose, one kernel. Blocks 0..2047: pack+zero; 2048..2063: rootT.
// ---------------------------------------------------------------------------
__global__ __launch_bounds__(256)
void prep_k(const int* __restrict__ mraw, unsigned int* __restrict__ pm,
            const float* __restrict__ root, float* __restrict__ rootT,
            float* __restrict__ aggr)
{
    __shared__ float T[64][65];
    const int bid = blockIdx.x;
    if (bid < 2048) {
        const int t = bid * 256 + threadIdx.x;
        aggr[t] = 0.f;
        const int row = t >> 7, wb = t & 127;
        unsigned int bits = 0;
        const uint4* p = (const uint4*)(mraw + (size_t)row * 4096 + wb * 32);
        #pragma unroll
        for (int g = 0; g < 8; g++) {
            const uint4 v = p[g];
            if (v.x) bits |= 1u << (g*4+0);
            if (v.y) bits |= 1u << (g*4+1);
            if (v.z) bits |= 1u << (g*4+2);
            if (v.w) bits |= 1u << (g*4+3);
        }
        pm[t] = bits;
    } else {
        const int bt = bid - 2048;
        const int m0 = (bt >> 2) * 64, n0 = (bt & 3) * 64;
        const int r = threadIdx.x >> 6, c = threadIdx.x & 63;
        #pragma unroll
        for (int i = 0; i < 16; i++)
            T[r + i*4][c] = root[(size_t)(m0 + r + i*4) * 256 + n0 + c];
        __syncthreads();
        #pragma unroll
        for (int i = 0; i < 16; i++)
            rootT[(size_t)(n0 + r + i*4) * 256 + m0 + c] = T[c][r + i*4];
    }
}

// ---------------------------------------------------------------------------
// MFMA bf16 flash attention (r14 validated 52.9us): swapped QK^T; fixed-shift
// base-2 softmax (q pre-scaled by log2e/sqrt(32), p = hw_exp2(s - 12*log2e));
// in-block split-K x2 strided; dbuf K/V; setprio; mask prefetch; additive
// merge. DO NOT widen split-K (r9/r5 L2 collapse); exp2f is OCML (r13).
// ---------------------------------------------------------------------------
__global__ __launch_bounds__(512, 4)
void attn_k(const short* __restrict__ qkvb, const short* __restrict__ vt,
            const unsigned int* __restrict__ pmask, float* __restrict__ o)
{
    __shared__ char lds[49152];
    const int tid = threadIdx.x;
    const int w2 = tid >> 6, l = tid & 63;
    const int g = l >> 4, ln = l & 15;
    const int gi = w2 >> 2, wq = w2 & 3;
    const int head = blockIdx.x >> 6;
    const int q0 = (blockIdx.x & 63) * 64;
    const int qa = q0 + wq * 16 + ln;

    const bf16x8_t qf = *(const bf16x8_t*)(qkvb + (size_t)qa*768 + head*32 + g*8);

    f32x4_t oT0 = {0.f,0.f,0.f,0.f};
    f32x4_t oT1 = {0.f,0.f,0.f,0.f};
    float lsum = 0.f;

    const int st = tid & 255;
    const int skey = st >> 2, sc = st & 3;
    const int sd = st >> 3, skc = st & 7;
    const short* kgp = qkvb + 256 + head*32 + sc*8;
    const short* vgp = vt + (size_t)head*131072 + (size_t)sd*4096 + skc*8;
    char* Kg = lds + gi*8192;
    char* Vg = lds + 16384 + gi*8192;
    char* Pw = lds + 32768 + w2*2048;
    const unsigned int* mrow = pmask + (size_t)qa*128;
    const int kswz = (skey & 7) << 4, vswz = (sd & 7) << 4;
    const int pswz = (ln & 7) << 4;

    uint2 mwc;
    {   // stage this group's first tile (tt = gi) -> buf 0; preload its mask
        const int k0 = gi * 64;
        const bf16x8_t kv = *(const bf16x8_t*)(kgp + (size_t)(k0 + skey)*768);
        *(bf16x8_t*)(Kg + ((skey*64 + sc*16) ^ kswz)) = kv;
        const bf16x8_t vv = *(const bf16x8_t*)(vgp + k0);
        *(bf16x8_t*)(Vg + ((sd*128 + skc*16) ^ vswz)) = vv;
        mwc = *(const uint2*)(mrow + gi*2);
    }

    for (int i = 0; i < 32; ++i) {
        __syncthreads();
        const int cur = i & 1;
        const int tt = 2*i + gi;
        uint2 mwn;
        if (i < 31) {   // prefetch this group's next tile (tt+2) + its mask
            const int k0n = (tt + 2) * 64;
            const bf16x8_t kv = *(const bf16x8_t*)(kgp + (size_t)(k0n + skey)*768);
            *(bf16x8_t*)(Kg + (cur^1)*4096 + ((skey*64 + sc*16) ^ kswz)) = kv;
            const bf16x8_t vv = *(const bf16x8_t*)(vgp + k0n);
            *(bf16x8_t*)(Vg + (cur^1)*4096 + ((sd*128 + skc*16) ^ vswz)) = vv;
            mwn = *(const uint2*)(mrow + (tt + 2)*2);
        }
        char* Kb = Kg + cur*4096;
        char* Vb = Vg + cur*4096;

        // S^T = mfma(K, Q): col=q=ln, rows = keys kt*16+g*4+r
        f32x4_t s[4];
        __builtin_amdgcn_s_setprio(1);
        #pragma unroll
        for (int kt = 0; kt < 4; kt++) {
            const int key = kt*16 + ln;
            const bf16x8_t kf = *(const bf16x8_t*)(Kb + ((key*64 + g*16) ^ ((key & 7) << 4)));
            f32x4_t z = {0.f,0.f,0.f,0.f};
            s[kt] = __builtin_amdgcn_mfma_f32_16x16x32_bf16(kf, qf, z, 0, 0, 0);
        }
        __builtin_amdgcn_s_setprio(0);

        // fixed-shift masked exp2 (raw v_exp_f32); lsum; pack P -> LDS
        #pragma unroll
        for (int kt = 0; kt < 4; kt++) {
            const unsigned word = (kt < 2) ? mwc.x : mwc.y;
            float p[4];
            #pragma unroll
            for (int r = 0; r < 4; r++) {
                const float e = hw_exp2(s[kt][r] - 17.312340490667562f);  // 12*log2e
                p[r] = ((word >> ((kt & 1)*16 + g*4 + r)) & 1u) ? e : 0.f;
            }
            lsum += (p[0] + p[1]) + (p[2] + p[3]);
            uint2 pk;
            pk.x = cvtpk_bf16(p[0], p[1]);
            pk.y = cvtpk_bf16(p[2], p[3]);
            *(uint2*)(Pw + ((ln*128 + kt*32 + g*8) ^ pswz)) = pk;
        }

        // PV: O^T += Vt . P
        __builtin_amdgcn_s_setprio(1);
        #pragma unroll
        for (int kh = 0; kh < 2; kh++) {
            const bf16x8_t pf = *(const bf16x8_t*)(Pw + ((ln*128 + kh*64 + g*16) ^ pswz));
            const bf16x8_t vf0 = *(const bf16x8_t*)(Vb + ((ln*128 + kh*64 + g*16) ^ pswz));
            const bf16x8_t vf1 = *(const bf16x8_t*)(Vb + (((16+ln)*128 + kh*64 + g*16) ^ pswz));
            oT0 = __builtin_amdgcn_mfma_f32_16x16x32_bf16(vf0, pf, oT0, 0, 0, 0);
            oT1 = __builtin_amdgcn_mfma_f32_16x16x32_bf16(vf1, pf, oT1, 0, 0, 0);
        }
        __builtin_amdgcn_s_setprio(0);
        mwc = mwn;
    }

    // ---- additive merge of the two key-group partials ----
    __syncthreads();
    *(f32x4_t*)(lds + w2*2048 + l*32)      = oT0;
    *(f32x4_t*)(lds + w2*2048 + l*32 + 16) = oT1;
    ((float*)(lds + 16384))[w2*64 + l] = lsum;
    __syncthreads();
    if (gi == 0) {
        const int pw = w2 + 4;
        const f32x4_t b0 = *(const f32x4_t*)(lds + pw*2048 + l*32);
        const f32x4_t b1 = *(const f32x4_t*)(lds + pw*2048 + l*32 + 16);
        const float lp = ((const float*)(lds + 16384))[pw*64 + l];
        oT0 += b0; oT1 += b1;
        lsum += lp;
        lsum += __shfl_xor(lsum, 16);
        lsum += __shfl_xor(lsum, 32);
        const float inv = 1.0f / fmaxf(lsum, 1e-37f);
        float* op = o + (size_t)qa * 256 + head*32;
        float4 v0 = {oT0[0]*inv, oT0[1]*inv, oT0[2]*inv, oT0[3]*inv};
        float4 v1 = {oT1[0]*inv, oT1[1]*inv, oT1[2]*inv, oT1[3]*inv};
        *(float4*)(op + g*4) = v0;
        *(float4*)(op + 16 + g*4) = v1;
    }
}

// ---------------------------------------------------------------------------
// LayerNorm over 256 dims, one block per row.
// ---------------------------------------------------------------------------
__global__ __launch_bounds__(256)
void ln_k(const float* __restrict__ in, const float* __restrict__ g,
          const float* __restrict__ b, float* __restrict__ out)
{
    const int n = blockIdx.x, t = threadIdx.x;
    const float v = in[(size_t)n * 256 + t];
    float s1 = v, s2 = v * v;
    #pragma unroll
    for (int off = 32; off > 0; off >>= 1) {
        s1 += __shfl_xor(s1, off);
        s2 += __shfl_xor(s2, off);
    }
    __shared__ float r1[4], r2[4];
    const int wv = t >> 6;
    if ((t & 63) == 0) { r1[wv] = s1; r2[wv] = s2; }
    __syncthreads();
    const float t1 = r1[0] + r1[1] + r1[2] + r1[3];
    const float t2 = r2[0] + r2[1] + r2[2] + r2[3];
    const float mu  = t1 * (1.0f / 256.0f);
    const float var = t2 * (1.0f / 256.0f) - mu * mu;
    const float rs  = rsqrtf(var + 1e-5f);
    out[(size_t)n * 256 + t] = (v - mu) * rs * g[t] + b[t];
}

// ---------------------------------------------------------------------------
extern "C" void kernel_launch(void* const* d_in, const int* in_sizes, int n_in,
                              void* d_out, int out_size, void* d_ws, size_t ws_size,
                              hipStream_t stream)
{
    const float* x     = (const float*)d_in[0];
    const int*   ei    = (const int*)  d_in[1];
    const float* eattr = (const float*)d_in[2];
    const int*   mask  = (const int*)  d_in[3];
    const float* W1   = (const float*)d_in[4];
    const float* b1   = (const float*)d_in[5];
    const float* W2   = (const float*)d_in[6];
    const float* b2   = (const float*)d_in[7];
    const float* ipw  = (const float*)d_in[8];
    const float* ipb  = (const float*)d_in[9];
    const float* ow   = (const float*)d_in[10];
    const float* ob   = (const float*)d_in[11];
    const float* root = (const float*)d_in[12];
    const float* bp   = (const float*)d_in[13];
    const float* ln1g = (const float*)d_in[14];
    const float* ln1b = (const float*)d_in[15];
    const float* ln2g = (const float*)d_in[16];
    const float* ln2b = (const float*)d_in[17];
    const float* linw = (const float*)d_in[18];
    const float* linb = (const float*)d_in[19];
    const int* ei0 = ei;
    const int* ei1 = ei + E_;

    float* ws = (float*)d_ws;
    short* h1b   = (short*)ws;                      // [E,256] bf16
    short* hb    = (short*)(ws + 524288);           // [E,256] bf16
    float* o     = ws + 1048576;                    // [E,256] f32 (attn out)
    float* y1    = ws + 1048576;                    //   reuse: o dead after S5
    float* z     = ws + 1572864;                    //   reuse: o dead after S5
    short* qkvb  = (short*)(ws + 2097152);          // [E,768] bf16 (q pre-scaled)
    float* aggr  = ws + 3670016;                    // [N,256] f32
    float* outb  = ws + 4194304;                    // [N,256] f32
    unsigned int* pmask = (unsigned int*)(ws + 4718592);  // [4096][128] bits
    short* vt    = (short*)(ws + 5242896);          // [8][32][4096] bf16
    float* rootT = ws + 5767184;                    // [256][256] f32

    dim3 blk(256);
    // prep: mask bits + aggr zero + rootT
    prep_k<<<dim3(2064), blk, 0, stream>>>(mask, pmask, root, rootT, aggr);

    // S1: h1b = bf16(leakyrelu(cat(x_i,x_j,eattr) @ W1^T + b1))   [MFMA]
    mgemm_k<1,true,false,false,false,1><<<dim3(64,4), blk, 0, stream>>>(
        nullptr, W1, b1, nullptr, h1b, nullptr, E_, 256, 768, ei0, ei1, x, eattr, 1.0f);
    // S2: hb = bf16(h1b @ W2^T + b2)   [MFMA, bf16 A]
    mgemm_k<0,false,false,false,true,1><<<dim3(64,4), blk, 0, stream>>>(
        h1b, W2, b2, nullptr, hb, nullptr, E_, 256, 256, nullptr, nullptr, nullptr, nullptr, 1.0f);
    // S3: qkvb + vt = hb @ in_proj_w^T + b; q scaled by log2e/sqrt(32);
    //     V columns written transposed into vt (vtrans folded in)
    mgemm_k<0,false,false,false,true,2><<<dim3(64,12), blk, 0, stream>>>(
        hb, ipw, ipb, nullptr, qkvb, vt, E_, 768, 256, nullptr, nullptr, nullptr, nullptr,
        0.25503486f);   // log2(e)/sqrt(32)
    // S4: MFMA flash attention -> o (f32)
    attn_k<<<dim3(512), dim3(512), 0, stream>>>(qkvb, vt, pmask, o);
    // S5: msg = o @ out_w^T + out_b, scatter-add to aggr   [MFMA]
    mgemm_k<0,false,true,false,false,0><<<dim3(64,4), blk, 0, stream>>>(
        o, ow, ob, nullptr, aggr, nullptr, E_, 256, 256, nullptr, ei1, nullptr, nullptr, 1.0f);
    // S6: outb = x @ root + aggr + bias_p   [MFMA + exact f32 add]
    mgemm_k<0,false,false,true,false,0><<<dim3(32,4), blk, 0, stream>>>(
        x, rootT, bp, aggr, outb, nullptr, NN_, 256, 256, nullptr, nullptr, nullptr, nullptr, 1.0f);
    // LN1
    ln_k<<<dim3(2048), blk, 0, stream>>>(outb, ln1g, ln1b, y1);
    // F2: z = y1 + y1 @ lin_w^T + lin_b   [MFMA + exact f32 residual]
    mgemm_k<0,false,false,true,false,0><<<dim3(32,4), blk, 0, stream>>>(
        y1, linw, linb, y1, z, nullptr, NN_, 256, 256, nullptr, nullptr, nullptr, nullptr, 1.0f);
    // LN2 -> out
    ln_k<<<dim3(2048), blk, 0, stream>>>(z, ln2g, ln2b, (float*)d_out);
}

// Round 16
// 110.601 us; speedup vs baseline: 1.2441x; 1.0523x over previous
//
#include <hip/hip_runtime.h>
#include <hip/hip_bf16.h>
#include <cstdint>

#define D_   256
#define E_   4096
#define NN_  2048

typedef float f32x4_t __attribute__((ext_vector_type(4)));
typedef short bf16x8_t __attribute__((ext_vector_type(8)));
typedef short bf16x4_t __attribute__((ext_vector_type(4)));

__device__ inline short f2bf(float f) {
    union { float fv; unsigned u; } v; v.fv = f;
    unsigned r = v.u + 0x7fffu + ((v.u >> 16) & 1u);
    return (short)(r >> 16);
}

__device__ inline unsigned cvtpk_bf16(float lo, float hi) {
    unsigned r;
    asm("v_cvt_pk_bf16_f32 %0, %1, %2" : "=v"(r) : "v"(lo), "v"(hi));
    return r;
}

// Raw hardware exp2: v_exp_f32 computes 2^x in one transcendental op.
// (exp2f() is the PRECISE OCML call — cost ~15us/attn, r13 lesson.)
__device__ inline float hw_exp2(float x) {
    float r;
    asm("v_exp_f32 %0, %1" : "=v"(r) : "v"(x));
    return r;
}

// ---------------------------------------------------------------------------
// bf16 MFMA GEMM, BK=64, 8 waves (r16): C = epi(A @ Bm^T + bias), 64x64 tile,
// 512 threads. Each wave owns a 16x32 sub-tile (wr=w>>1 row-group of 16,
// wc=w&1 col-group of 32; 2 accum frags, 4 MFMA/K-step). Same tile/traffic
// as r15's 4-wave version but 2x wave parallelism (mgemm grids are <=256
// blocks = 1 block/CU — latency-bound at 12.5% occupancy; this doubles it).
// Staging: one bf16x8 per matrix per thread. dbuf LDS 32KB, 1 barrier/K-step.
// ABF16: A is bf16. OUT: 0=f32 C, 1=bf16 C (cols<256 scaled by qsc),
// 2=qkv split (cols<512 -> qkvb; cols 512.. -> vt transposed).
// SCATTER: f32 atomicAdd via ei1. HASADD: += addsrc (f32, exact).
// ---------------------------------------------------------------------------
template<int ACT, bool GATHER, bool SCATTER, bool HASADD, bool ABF16, int OUT>
__global__ __launch_bounds__(512)
void mgemm_k(const void* __restrict__ A, const float* __restrict__ Bm,
             const float* __restrict__ bias, const float* __restrict__ addsrc,
             void* __restrict__ C, short* __restrict__ vtb,
             int M, int N, int K,
             const int* __restrict__ ei0, const int* __restrict__ ei1,
             const float* __restrict__ x, const float* __restrict__ eattr,
             float qsc)
{
    __shared__ char lds[32768];   // A dbuf 2x8KB @0, B dbuf 2x8KB @16384
    const int tid = threadIdx.x;
    const int w = tid >> 6, l = tid & 63;
    const int g = l >> 4, ln = l & 15;
    const int wr = w >> 1, wc = w & 1;          // wr 0..3 (16-row), wc 0..1 (32-col)
    const int m0 = blockIdx.x * 64, n0 = blockIdx.y * 64;

    const int srow = tid >> 3;                  // staging row 0..63
    const int sck  = (tid & 7) * 8;             // staging col chunk (8 elements)
    const int sswz = (srow & 7) << 4;
    int gi1 = 0, gi0 = 0;
    if (GATHER) { gi1 = ei1[m0 + srow]; gi0 = ei0[m0 + srow]; }

    f32x4_t acc[2];
    acc[0] = f32x4_t{0.f,0.f,0.f,0.f};
    acc[1] = f32x4_t{0.f,0.f,0.f,0.f};

    const int nt = K >> 6;
    float4 ga[2], gb[2];
    bf16x8_t gab;

    auto loadG = [&](int kk) {
        const int cb = kk + sck;   // 8-aligned: never straddles gather regions
        if (ABF16) {
            gab = *(const bf16x8_t*)((const short*)A + (size_t)(m0 + srow) * K + cb);
        } else {
            const float* src;
            if (GATHER) {
                if (cb < 256)      src = x + (size_t)gi1 * 256 + cb;
                else if (cb < 512) src = x + (size_t)gi0 * 256 + (cb - 256);
                else               src = eattr + (size_t)(m0 + srow) * 256 + (cb - 512);
            } else {
                src = (const float*)A + (size_t)(m0 + srow) * K + cb;
            }
            ga[0] = *(const float4*)src;
            ga[1] = *(const float4*)(src + 4);
        }
        const float* bsrc = Bm + (size_t)(n0 + srow) * K + cb;
        gb[0] = *(const float4*)bsrc;
        gb[1] = *(const float4*)(bsrc + 4);
    };
    auto writeS = [&](int buf) {
        const int off = (srow*128 + sck*2) ^ sswz;
        if (ABF16) {
            *(bf16x8_t*)(lds + buf*8192 + off) = gab;
        } else {
            uint4 pa;
            pa.x = cvtpk_bf16(ga[0].x, ga[0].y); pa.y = cvtpk_bf16(ga[0].z, ga[0].w);
            pa.z = cvtpk_bf16(ga[1].x, ga[1].y); pa.w = cvtpk_bf16(ga[1].z, ga[1].w);
            *(uint4*)(lds + buf*8192 + off) = pa;
        }
        uint4 pb;
        pb.x = cvtpk_bf16(gb[0].x, gb[0].y); pb.y = cvtpk_bf16(gb[0].z, gb[0].w);
        pb.z = cvtpk_bf16(gb[1].x, gb[1].y); pb.w = cvtpk_bf16(gb[1].z, gb[1].w);
        *(uint4*)(lds + 16384 + buf*8192 + off) = pb;
    };

    loadG(0);
    writeS(0);
    __syncthreads();
    int cur = 0;
    for (int t = 0; t < nt; ++t) {
        if (t + 1 < nt) loadG((t + 1) << 6);
        #pragma unroll
        for (int kc = 0; kc < 2; kc++) {
            const int arow = wr*16 + ln;
            const bf16x8_t af = *(const bf16x8_t*)(lds + cur*8192 +
                    ((arow*128 + kc*64 + g*16) ^ ((arow&7)<<4)));
            #pragma unroll
            for (int n = 0; n < 2; n++) {
                const int brow = wc*32 + n*16 + ln;
                const bf16x8_t bfr = *(const bf16x8_t*)(lds + 16384 + cur*8192 +
                         ((brow*128 + kc*64 + g*16) ^ ((brow&7)<<4)));
                acc[n] = __builtin_amdgcn_mfma_f32_16x16x32_bf16(af, bfr, acc[n], 0, 0, 0);
            }
        }
        if (t + 1 < nt) writeS(cur ^ 1);
        __syncthreads();
        cur ^= 1;
    }

    #pragma unroll
    for (int n = 0; n < 2; n++) {
        const int col = n0 + wc*32 + n*16 + ln;
        const float bv = bias[col];
        const int row0 = m0 + wr*16 + g*4;
        float pv[4];
        #pragma unroll
        for (int r = 0; r < 4; r++) {
            float v = acc[n][r] + bv;
            if (ACT == 1) v = v > 0.f ? v : 0.2f * v;
            if (HASADD) v += addsrc[(size_t)(row0 + r) * N + col];
            pv[r] = v;
        }
        if (SCATTER) {
            #pragma unroll
            for (int r = 0; r < 4; r++)
                atomicAdd(&((float*)C)[(size_t)ei1[row0 + r] * 256 + col], pv[r]);
        } else if (OUT == 0) {
            #pragma unroll
            for (int r = 0; r < 4; r++)
                ((float*)C)[(size_t)(row0 + r) * N + col] = pv[r];
        } else if (OUT == 1) {
            #pragma unroll
            for (int r = 0; r < 4; r++)
                ((short*)C)[(size_t)(row0 + r) * N + col] =
                    f2bf((col < 256) ? pv[r] * qsc : pv[r]);
        } else {   // OUT == 2: qkv split
            if (col < 512) {
                #pragma unroll
                for (int r = 0; r < 4; r++)
                    ((short*)C)[(size_t)(row0 + r) * 768 + col] =
                        f2bf((col < 256) ? pv[r] * qsc : pv[r]);
            } else {
                const int hd = (col - 512) >> 5, d = (col - 512) & 31;
                bf16x4_t pk;
                #pragma unroll
                for (int r = 0; r < 4; r++) pk[r] = f2bf(pv[r]);
                *(bf16x4_t*)(vtb + (size_t)hd*131072 + (size_t)d*4096 + row0) = pk;
            }
        }
    }
}

// ---------------------------------------------------------------------------
// Prep: mask bit-pack (int32 0/1 layout, established r1->r2 A/B) + aggr zero
// + root transpose, one kernel. Blocks 0..2047: pack+zero; 2048..2063: rootT.
// ---------------------------------------------------------------------------
__global__ __launch_bounds__(256)
void prep_k(const int* __restrict__ mraw, unsigned int* __restrict__ pm,
            const float* __restrict__ root, float* __restrict__ rootT,
            float* __restrict__ aggr)
{
    __shared__ float T[64][65];
    const int bid = blockIdx.x;
    if (bid < 2048) {
        const int t = bid * 256 + threadIdx.x;
        aggr[t] = 0.f;
        const int row = t >> 7, wb = t & 127;
        unsigned int bits = 0;
        const uint4* p = (const uint4*)(mraw + (size_t)row * 4096 + wb * 32);
        #pragma unroll
        for (int g = 0; g < 8; g++) {
            const uint4 v = p[g];
            if (v.x) bits |= 1u << (g*4+0);
            if (v.y) bits |= 1u << (g*4+1);
            if (v.z) bits |= 1u << (g*4+2);
            if (v.w) bits |= 1u << (g*4+3);
        }
        pm[t] = bits;
    } else {
        const int bt = bid - 2048;
        const int m0 = (bt >> 2) * 64, n0 = (bt & 3) * 64;
        const int r = threadIdx.x >> 6, c = threadIdx.x & 63;
        #pragma unroll
        for (int i = 0; i < 16; i++)
            T[r + i*4][c] = root[(size_t)(m0 + r + i*4) * 256 + n0 + c];
        __syncthreads();
        #pragma unroll
        for (int i = 0; i < 16; i++)
            rootT[(size_t)(n0 + r + i*4) * 256 + m0 + c] = T[c][r + i*4];
    }
}

// ---------------------------------------------------------------------------
// MFMA bf16 flash attention (r14 validated 52.9us): swapped QK^T; fixed-shift
// base-2 softmax (q pre-scaled by log2e/sqrt(32), p = hw_exp2(s - 12*log2e));
// in-block split-K x2 strided; dbuf K/V; setprio; mask prefetch; additive
// merge. DO NOT widen split-K (r9/r5 L2 collapse); exp2f is OCML (r13).
// ---------------------------------------------------------------------------
__global__ __launch_bounds__(512, 4)
void attn_k(const short* __restrict__ qkvb, const short* __restrict__ vt,
            const unsigned int* __restrict__ pmask, float* __restrict__ o)
{
    __shared__ char lds[49152];
    const int tid = threadIdx.x;
    const int w2 = tid >> 6, l = tid & 63;
    const int g = l >> 4, ln = l & 15;
    const int gi = w2 >> 2, wq = w2 & 3;
    const int head = blockIdx.x >> 6;
    const int q0 = (blockIdx.x & 63) * 64;
    const int qa = q0 + wq * 16 + ln;

    const bf16x8_t qf = *(const bf16x8_t*)(qkvb + (size_t)qa*768 + head*32 + g*8);

    f32x4_t oT0 = {0.f,0.f,0.f,0.f};
    f32x4_t oT1 = {0.f,0.f,0.f,0.f};
    float lsum = 0.f;

    const int st = tid & 255;
    const int skey = st >> 2, sc = st & 3;
    const int sd = st >> 3, skc = st & 7;
    const short* kgp = qkvb + 256 + head*32 + sc*8;
    const short* vgp = vt + (size_t)head*131072 + (size_t)sd*4096 + skc*8;
    char* Kg = lds + gi*8192;
    char* Vg = lds + 16384 + gi*8192;
    char* Pw = lds + 32768 + w2*2048;
    const unsigned int* mrow = pmask + (size_t)qa*128;
    const int kswz = (skey & 7) << 4, vswz = (sd & 7) << 4;
    const int pswz = (ln & 7) << 4;

    uint2 mwc;
    {   // stage this group's first tile (tt = gi) -> buf 0; preload its mask
        const int k0 = gi * 64;
        const bf16x8_t kv = *(const bf16x8_t*)(kgp + (size_t)(k0 + skey)*768);
        *(bf16x8_t*)(Kg + ((skey*64 + sc*16) ^ kswz)) = kv;
        const bf16x8_t vv = *(const bf16x8_t*)(vgp + k0);
        *(bf16x8_t*)(Vg + ((sd*128 + skc*16) ^ vswz)) = vv;
        mwc = *(const uint2*)(mrow + gi*2);
    }

    for (int i = 0; i < 32; ++i) {
        __syncthreads();
        const int cur = i & 1;
        const int tt = 2*i + gi;
        uint2 mwn;
        if (i < 31) {   // prefetch this group's next tile (tt+2) + its mask
            const int k0n = (tt + 2) * 64;
            const bf16x8_t kv = *(const bf16x8_t*)(kgp + (size_t)(k0n + skey)*768);
            *(bf16x8_t*)(Kg + (cur^1)*4096 + ((skey*64 + sc*16) ^ kswz)) = kv;
            const bf16x8_t vv = *(const bf16x8_t*)(vgp + k0n);
            *(bf16x8_t*)(Vg + (cur^1)*4096 + ((sd*128 + skc*16) ^ vswz)) = vv;
            mwn = *(const uint2*)(mrow + (tt + 2)*2);
        }
        char* Kb = Kg + cur*4096;
        char* Vb = Vg + cur*4096;

        // S^T = mfma(K, Q): col=q=ln, rows = keys kt*16+g*4+r
        f32x4_t s[4];
        __builtin_amdgcn_s_setprio(1);
        #pragma unroll
        for (int kt = 0; kt < 4; kt++) {
            const int key = kt*16 + ln;
            const bf16x8_t kf = *(const bf16x8_t*)(Kb + ((key*64 + g*16) ^ ((key & 7) << 4)));
            f32x4_t z = {0.f,0.f,0.f,0.f};
            s[kt] = __builtin_amdgcn_mfma_f32_16x16x32_bf16(kf, qf, z, 0, 0, 0);
        }
        __builtin_amdgcn_s_setprio(0);

        // fixed-shift masked exp2 (raw v_exp_f32); lsum; pack P -> LDS
        #pragma unroll
        for (int kt = 0; kt < 4; kt++) {
            const unsigned word = (kt < 2) ? mwc.x : mwc.y;
            float p[4];
            #pragma unroll
            for (int r = 0; r < 4; r++) {
                const float e = hw_exp2(s[kt][r] - 17.312340490667562f);  // 12*log2e
                p[r] = ((word >> ((kt & 1)*16 + g*4 + r)) & 1u) ? e : 0.f;
            }
            lsum += (p[0] + p[1]) + (p[2] + p[3]);
            uint2 pk;
            pk.x = cvtpk_bf16(p[0], p[1]);
            pk.y = cvtpk_bf16(p[2], p[3]);
            *(uint2*)(Pw + ((ln*128 + kt*32 + g*8) ^ pswz)) = pk;
        }

        // PV: O^T += Vt . P
        __builtin_amdgcn_s_setprio(1);
        #pragma unroll
        for (int kh = 0; kh < 2; kh++) {
            const bf16x8_t pf = *(const bf16x8_t*)(Pw + ((ln*128 + kh*64 + g*16) ^ pswz));
            const bf16x8_t vf0 = *(const bf16x8_t*)(Vb + ((ln*128 + kh*64 + g*16) ^ pswz));
            const bf16x8_t vf1 = *(const bf16x8_t*)(Vb + (((16+ln)*128 + kh*64 + g*16) ^ pswz));
            oT0 = __builtin_amdgcn_mfma_f32_16x16x32_bf16(vf0, pf, oT0, 0, 0, 0);
            oT1 = __builtin_amdgcn_mfma_f32_16x16x32_bf16(vf1, pf, oT1, 0, 0, 0);
        }
        __builtin_amdgcn_s_setprio(0);
        mwc = mwn;
    }

    // ---- additive merge of the two key-group partials ----
    __syncthreads();
    *(f32x4_t*)(lds + w2*2048 + l*32)      = oT0;
    *(f32x4_t*)(lds + w2*2048 + l*32 + 16) = oT1;
    ((float*)(lds + 16384))[w2*64 + l] = lsum;
    __syncthreads();
    if (gi == 0) {
        const int pw = w2 + 4;
        const f32x4_t b0 = *(const f32x4_t*)(lds + pw*2048 + l*32);
        const f32x4_t b1 = *(const f32x4_t*)(lds + pw*2048 + l*32 + 16);
        const float lp = ((const float*)(lds + 16384))[pw*64 + l];
        oT0 += b0; oT1 += b1;
        lsum += lp;
        lsum += __shfl_xor(lsum, 16);
        lsum += __shfl_xor(lsum, 32);
        const float inv = 1.0f / fmaxf(lsum, 1e-37f);
        float* op = o + (size_t)qa * 256 + head*32;
        float4 v0 = {oT0[0]*inv, oT0[1]*inv, oT0[2]*inv, oT0[3]*inv};
        float4 v1 = {oT1[0]*inv, oT1[1]*inv, oT1[2]*inv, oT1[3]*inv};
        *(float4*)(op + g*4) = v0;
        *(float4*)(op + 16 + g*4) = v1;
    }
}

// ---------------------------------------------------------------------------
// LayerNorm over 256 dims, one block per row.
// ---------------------------------------------------------------------------
__global__ __launch_bounds__(256)
void ln_k(const float* __restrict__ in, const float* __restrict__ g,
          const float* __restrict__ b, float* __restrict__ out)
{
    const int n = blockIdx.x, t = threadIdx.x;
    const float v = in[(size_t)n * 256 + t];
    float s1 = v, s2 = v * v;
    #pragma unroll
    for (int off = 32; off > 0; off >>= 1) {
        s1 += __shfl_xor(s1, off);
        s2 += __shfl_xor(s2, off);
    }
    __shared__ float r1[4], r2[4];
    const int wv = t >> 6;
    if ((t & 63) == 0) { r1[wv] = s1; r2[wv] = s2; }
    __syncthreads();
    const float t1 = r1[0] + r1[1] + r1[2] + r1[3];
    const float t2 = r2[0] + r2[1] + r2[2] + r2[3];
    const float mu  = t1 * (1.0f / 256.0f);
    const float var = t2 * (1.0f / 256.0f) - mu * mu;
    const float rs  = rsqrtf(var + 1e-5f);
    out[(size_t)n * 256 + t] = (v - mu) * rs * g[t] + b[t];
}

// ---------------------------------------------------------------------------
extern "C" void kernel_launch(void* const* d_in, const int* in_sizes, int n_in,
                              void* d_out, int out_size, void* d_ws, size_t ws_size,
                              hipStream_t stream)
{
    const float* x     = (const float*)d_in[0];
    const int*   ei    = (const int*)  d_in[1];
    const float* eattr = (const float*)d_in[2];
    const int*   mask  = (const int*)  d_in[3];
    const float* W1   = (const float*)d_in[4];
    const float* b1   = (const float*)d_in[5];
    const float* W2   = (const float*)d_in[6];
    const float* b2   = (const float*)d_in[7];
    const float* ipw  = (const float*)d_in[8];
    const float* ipb  = (const float*)d_in[9];
    const float* ow   = (const float*)d_in[10];
    const float* ob   = (const float*)d_in[11];
    const float* root = (const float*)d_in[12];
    const float* bp   = (const float*)d_in[13];
    const float* ln1g = (const float*)d_in[14];
    const float* ln1b = (const float*)d_in[15];
    const float* ln2g = (const float*)d_in[16];
    const float* ln2b = (const float*)d_in[17];
    const float* linw = (const float*)d_in[18];
    const float* linb = (const float*)d_in[19];
    const int* ei0 = ei;
    const int* ei1 = ei + E_;

    float* ws = (float*)d_ws;
    short* h1b   = (short*)ws;                      // [E,256] bf16
    short* hb    = (short*)(ws + 524288);           // [E,256] bf16
    float* o     = ws + 1048576;                    // [E,256] f32 (attn out)
    float* y1    = ws + 1048576;                    //   reuse: o dead after S5
    float* z     = ws + 1572864;                    //   reuse: o dead after S5
    short* qkvb  = (short*)(ws + 2097152);          // [E,768] bf16 (q pre-scaled)
    float* aggr  = ws + 3670016;                    // [N,256] f32
    float* outb  = ws + 4194304;                    // [N,256] f32
    unsigned int* pmask = (unsigned int*)(ws + 4718592);  // [4096][128] bits
    short* vt    = (short*)(ws + 5242896);          // [8][32][4096] bf16
    float* rootT = ws + 5767184;                    // [256][256] f32

    dim3 blk(256);
    dim3 blk512(512);
    // prep: mask bits + aggr zero + rootT
    prep_k<<<dim3(2064), blk, 0, stream>>>(mask, pmask, root, rootT, aggr);

    // S1: h1b = bf16(leakyrelu(cat(x_i,x_j,eattr) @ W1^T + b1))   [MFMA]
    mgemm_k<1,true,false,false,false,1><<<dim3(64,4), blk512, 0, stream>>>(
        nullptr, W1, b1, nullptr, h1b, nullptr, E_, 256, 768, ei0, ei1, x, eattr, 1.0f);
    // S2: hb = bf16(h1b @ W2^T + b2)   [MFMA, bf16 A]
    mgemm_k<0,false,false,false,true,1><<<dim3(64,4), blk512, 0, stream>>>(
        h1b, W2, b2, nullptr, hb, nullptr, E_, 256, 256, nullptr, nullptr, nullptr, nullptr, 1.0f);
    // S3: qkvb + vt = hb @ in_proj_w^T + b; q scaled by log2e/sqrt(32);
    //     V columns written transposed into vt (vtrans folded in)
    mgemm_k<0,false,false,false,true,2><<<dim3(64,12), blk512, 0, stream>>>(
        hb, ipw, ipb, nullptr, qkvb, vt, E_, 768, 256, nullptr, nullptr, nullptr, nullptr,
        0.25503486f);   // log2(e)/sqrt(32)
    // S4: MFMA flash attention -> o (f32)
    attn_k<<<dim3(512), dim3(512), 0, stream>>>(qkvb, vt, pmask, o);
    // S5: msg = o @ out_w^T + out_b, scatter-add to aggr   [MFMA]
    mgemm_k<0,false,true,false,false,0><<<dim3(64,4), blk512, 0, stream>>>(
        o, ow, ob, nullptr, aggr, nullptr, E_, 256, 256, nullptr, ei1, nullptr, nullptr, 1.0f);
    // S6: outb = x @ root + aggr + bias_p   [MFMA + exact f32 add]
    mgemm_k<0,false,false,true,false,0><<<dim3(32,4), blk512, 0, stream>>>(
        x, rootT, bp, aggr, outb, nullptr, NN_, 256, 256, nullptr, nullptr, nullptr, nullptr, 1.0f);
    // LN1
    ln_k<<<dim3(2048), blk, 0, stream>>>(outb, ln1g, ln1b, y1);
    // F2: z = y1 + y1 @ lin_w^T + lin_b   [MFMA + exact f32 residual]
    mgemm_k<0,false,false,true,false,0><<<dim3(32,4), blk512, 0, stream>>>(
        y1, linw, linb, y1, z, nullptr, NN_, 256, 256, nullptr, nullptr, nullptr, nullptr, 1.0f);
    // LN2 -> out
    ln_k<<<dim3(2048), blk, 0, stream>>>(z, ln2g, ln2b, (float*)d_out);
}

// Round 17
// 109.171 us; speedup vs baseline: 1.2604x; 1.0131x over previous
//
#include <hip/hip_runtime.h>
#include <hip/hip_bf16.h>
#include <cstdint>

#define D_   256
#define E_   4096
#define NN_  2048

typedef float f32x4_t __attribute__((ext_vector_type(4)));
typedef short bf16x8_t __attribute__((ext_vector_type(8)));
typedef short bf16x4_t __attribute__((ext_vector_type(4)));

__device__ inline short f2bf(float f) {
    union { float fv; unsigned u; } v; v.fv = f;
    unsigned r = v.u + 0x7fffu + ((v.u >> 16) & 1u);
    return (short)(r >> 16);
}

__device__ inline unsigned cvtpk_bf16(float lo, float hi) {
    unsigned r;
    asm("v_cvt_pk_bf16_f32 %0, %1, %2" : "=v"(r) : "v"(lo), "v"(hi));
    return r;
}

// Raw hardware exp2: v_exp_f32 computes 2^x in one transcendental op.
// (exp2f() is the PRECISE OCML call — cost ~15us/attn, r13 lesson.)
__device__ inline float hw_exp2(float x) {
    float r;
    asm("v_exp_f32 %0, %1" : "=v"(r) : "v"(x));
    return r;
}

// ---------------------------------------------------------------------------
// bf16 MFMA GEMM, BK=64, 8 waves, BM in {64,32} (r17).
// BM=64: wave = 16x32 sub-tile (2 frags); grid (M/64, N/64).
// BM=32: wave = 16x16 sub-tile (1 frag); grid (M/32, N/64) — used for the
//        M=2048 stages (S6/F2) whose BM=64 grid was 128 blocks = half the
//        CUs idle (latency-bound; 2x blocks beats bigger tiles there).
// dbuf LDS, 1 barrier/K-step. ABF16: A bf16. OUT: 0=f32, 1=bf16 (cols<256
// scaled by qsc), 2=qkv split (cols<512 -> qkvb; 512.. -> vt transposed).
// SCATTER: f32 atomicAdd via ei1. HASADD: += addsrc (f32, exact).
// ---------------------------------------------------------------------------
template<int BM, int ACT, bool GATHER, bool SCATTER, bool HASADD, bool ABF16, int OUT>
__global__ __launch_bounds__(512)
void mgemm_k(const void* __restrict__ A, const float* __restrict__ Bm,
             const float* __restrict__ bias, const float* __restrict__ addsrc,
             void* __restrict__ C, short* __restrict__ vtb,
             int M, int N, int K,
             const int* __restrict__ ei0, const int* __restrict__ ei1,
             const float* __restrict__ x, const float* __restrict__ eattr,
             float qsc)
{
    constexpr int ASZ  = BM * 128;        // bytes per A buffer
    constexpr int BOFF = 2 * ASZ;         // B dbuf base
    constexpr int NFR  = (BM == 64) ? 2 : 1;
    __shared__ char lds[BOFF + 16384];
    const int tid = threadIdx.x;
    const int w = tid >> 6, l = tid & 63;
    const int g = l >> 4, ln = l & 15;
    const int wr = (BM == 64) ? (w >> 1) : (w >> 2);
    const int wc = (BM == 64) ? (w & 1)  : (w & 3);
    const int m0 = blockIdx.x * BM, n0 = blockIdx.y * 64;

    const int srow = tid >> 3;                  // 0..63 (A uses 0..31 if BM=32)
    const int sck  = (tid & 7) * 8;
    const int sswz = (srow & 7) << 4;
    const bool doA = (BM == 64) || (tid < 256);
    int gi1 = 0, gi0 = 0;
    if (GATHER) { gi1 = ei1[m0 + srow]; gi0 = ei0[m0 + srow]; }

    f32x4_t acc[NFR];
    #pragma unroll
    for (int n = 0; n < NFR; n++) acc[n] = f32x4_t{0.f,0.f,0.f,0.f};

    const int nt = K >> 6;
    float4 ga[2], gb[2];
    bf16x8_t gab;

    auto loadG = [&](int kk) {
        const int cb = kk + sck;
        if (doA) {
            if (ABF16) {
                gab = *(const bf16x8_t*)((const short*)A + (size_t)(m0 + srow) * K + cb);
            } else {
                const float* src;
                if (GATHER) {
                    if (cb < 256)      src = x + (size_t)gi1 * 256 + cb;
                    else if (cb < 512) src = x + (size_t)gi0 * 256 + (cb - 256);
                    else               src = eattr + (size_t)(m0 + srow) * 256 + (cb - 512);
                } else {
                    src = (const float*)A + (size_t)(m0 + srow) * K + cb;
                }
                ga[0] = *(const float4*)src;
                ga[1] = *(const float4*)(src + 4);
            }
        }
        const float* bsrc = Bm + (size_t)(n0 + srow) * K + cb;
        gb[0] = *(const float4*)bsrc;
        gb[1] = *(const float4*)(bsrc + 4);
    };
    auto writeS = [&](int buf) {
        const int off = (srow*128 + sck*2) ^ sswz;
        if (doA) {
            if (ABF16) {
                *(bf16x8_t*)(lds + buf*ASZ + off) = gab;
            } else {
                uint4 pa;
                pa.x = cvtpk_bf16(ga[0].x, ga[0].y); pa.y = cvtpk_bf16(ga[0].z, ga[0].w);
                pa.z = cvtpk_bf16(ga[1].x, ga[1].y); pa.w = cvtpk_bf16(ga[1].z, ga[1].w);
                *(uint4*)(lds + buf*ASZ + off) = pa;
            }
        }
        uint4 pb;
        pb.x = cvtpk_bf16(gb[0].x, gb[0].y); pb.y = cvtpk_bf16(gb[0].z, gb[0].w);
        pb.z = cvtpk_bf16(gb[1].x, gb[1].y); pb.w = cvtpk_bf16(gb[1].z, gb[1].w);
        *(uint4*)(lds + BOFF + buf*8192 + off) = pb;
    };

    loadG(0);
    writeS(0);
    __syncthreads();
    int cur = 0;
    for (int t = 0; t < nt; ++t) {
        if (t + 1 < nt) loadG((t + 1) << 6);
        #pragma unroll
        for (int kc = 0; kc < 2; kc++) {
            const int arow = wr*16 + ln;
            const bf16x8_t af = *(const bf16x8_t*)(lds + cur*ASZ +
                    ((arow*128 + kc*64 + g*16) ^ ((arow&7)<<4)));
            #pragma unroll
            for (int n = 0; n < NFR; n++) {
                const int brow = (BM == 64 ? wc*32 + n*16 : wc*16) + ln;
                const bf16x8_t bfr = *(const bf16x8_t*)(lds + BOFF + cur*8192 +
                         ((brow*128 + kc*64 + g*16) ^ ((brow&7)<<4)));
                acc[n] = __builtin_amdgcn_mfma_f32_16x16x32_bf16(af, bfr, acc[n], 0, 0, 0);
            }
        }
        if (t + 1 < nt) writeS(cur ^ 1);
        __syncthreads();
        cur ^= 1;
    }

    #pragma unroll
    for (int n = 0; n < NFR; n++) {
        const int col = n0 + (BM == 64 ? wc*32 + n*16 : wc*16) + ln;
        const float bv = bias[col];
        const int row0 = m0 + wr*16 + g*4;
        float pv[4];
        #pragma unroll
        for (int r = 0; r < 4; r++) {
            float v = acc[n][r] + bv;
            if (ACT == 1) v = v > 0.f ? v : 0.2f * v;
            if (HASADD) v += addsrc[(size_t)(row0 + r) * N + col];
            pv[r] = v;
        }
        if (SCATTER) {
            #pragma unroll
            for (int r = 0; r < 4; r++)
                atomicAdd(&((float*)C)[(size_t)ei1[row0 + r] * 256 + col], pv[r]);
        } else if (OUT == 0) {
            #pragma unroll
            for (int r = 0; r < 4; r++)
                ((float*)C)[(size_t)(row0 + r) * N + col] = pv[r];
        } else if (OUT == 1) {
            #pragma unroll
            for (int r = 0; r < 4; r++)
                ((short*)C)[(size_t)(row0 + r) * N + col] =
                    f2bf((col < 256) ? pv[r] * qsc : pv[r]);
        } else {   // OUT == 2: qkv split
            if (col < 512) {
                #pragma unroll
                for (int r = 0; r < 4; r++)
                    ((short*)C)[(size_t)(row0 + r) * 768 + col] =
                        f2bf((col < 256) ? pv[r] * qsc : pv[r]);
            } else {
                const int hd = (col - 512) >> 5, d = (col - 512) & 31;
                bf16x4_t pk;
                #pragma unroll
                for (int r = 0; r < 4; r++) pk[r] = f2bf(pv[r]);
                *(bf16x4_t*)(vtb + (size_t)hd*131072 + (size_t)d*4096 + row0) = pk;
            }
        }
    }
}

// ---------------------------------------------------------------------------
// Prep: mask bit-pack (int32 0/1 layout, established r1->r2 A/B) + aggr zero
// + root transpose, one kernel. Blocks 0..2047: pack+zero; 2048..2063: rootT.
// ---------------------------------------------------------------------------
__global__ __launch_bounds__(256)
void prep_k(const int* __restrict__ mraw, unsigned int* __restrict__ pm,
            const float* __restrict__ root, float* __restrict__ rootT,
            float* __restrict__ aggr)
{
    __shared__ float T[64][65];
    const int bid = blockIdx.x;
    if (bid < 2048) {
        const int t = bid * 256 + threadIdx.x;
        aggr[t] = 0.f;
        const int row = t >> 7, wb = t & 127;
        unsigned int bits = 0;
        const uint4* p = (const uint4*)(mraw + (size_t)row * 4096 + wb * 32);
        #pragma unroll
        for (int g = 0; g < 8; g++) {
            const uint4 v = p[g];
            if (v.x) bits |= 1u << (g*4+0);
            if (v.y) bits |= 1u << (g*4+1);
            if (v.z) bits |= 1u << (g*4+2);
            if (v.w) bits |= 1u << (g*4+3);
        }
        pm[t] = bits;
    } else {
        const int bt = bid - 2048;
        const int m0 = (bt >> 2) * 64, n0 = (bt & 3) * 64;
        const int r = threadIdx.x >> 6, c = threadIdx.x & 63;
        #pragma unroll
        for (int i = 0; i < 16; i++)
            T[r + i*4][c] = root[(size_t)(m0 + r + i*4) * 256 + n0 + c];
        __syncthreads();
        #pragma unroll
        for (int i = 0; i < 16; i++)
            rootT[(size_t)(n0 + r + i*4) * 256 + m0 + c] = T[c][r + i*4];
    }
}

// ---------------------------------------------------------------------------
// MFMA bf16 flash attention (r14 structure; r17: lsum via ones-MFMA).
// Swapped QK^T; fixed-shift base-2 softmax (q pre-scaled by log2e/sqrt(32),
// p = hw_exp2(s - 12*log2e)); in-block split-K x2 strided; dbuf K/V; setprio;
// mask prefetch; additive merge. lsum accumulated by oS = mfma(ones, P, oS)
// on the matrix pipe (MFMA K-reduce => every lane holds the group total; the
// old 16 VALU adds/tile + final cross-lane shuffles are deleted).
// DO NOT widen split-K (r9/r5 L2 collapse); exp2f is OCML (r13).
// ---------------------------------------------------------------------------
__global__ __launch_bounds__(512, 4)
void attn_k(const short* __restrict__ qkvb, const short* __restrict__ vt,
            const unsigned int* __restrict__ pmask, float* __restrict__ o)
{
    __shared__ char lds[49152];
    const int tid = threadIdx.x;
    const int w2 = tid >> 6, l = tid & 63;
    const int g = l >> 4, ln = l & 15;
    const int gi = w2 >> 2, wq = w2 & 3;
    const int head = blockIdx.x >> 6;
    const int q0 = (blockIdx.x & 63) * 64;
    const int qa = q0 + wq * 16 + ln;

    const bf16x8_t qf = *(const bf16x8_t*)(qkvb + (size_t)qa*768 + head*32 + g*8);
    bf16x8_t ones;
    #pragma unroll
    for (int j = 0; j < 8; j++) ones[j] = (short)0x3F80;   // bf16 1.0

    f32x4_t oT0 = {0.f,0.f,0.f,0.f};
    f32x4_t oT1 = {0.f,0.f,0.f,0.f};
    f32x4_t oS  = {0.f,0.f,0.f,0.f};   // lsum accumulator (all rows identical)

    const int st = tid & 255;
    const int skey = st >> 2, sc = st & 3;
    const int sd = st >> 3, skc = st & 7;
    const short* kgp = qkvb + 256 + head*32 + sc*8;
    const short* vgp = vt + (size_t)head*131072 + (size_t)sd*4096 + skc*8;
    char* Kg = lds + gi*8192;
    char* Vg = lds + 16384 + gi*8192;
    char* Pw = lds + 32768 + w2*2048;
    const unsigned int* mrow = pmask + (size_t)qa*128;
    const int kswz = (skey & 7) << 4, vswz = (sd & 7) << 4;
    const int pswz = (ln & 7) << 4;

    uint2 mwc;
    {   // stage this group's first tile (tt = gi) -> buf 0; preload its mask
        const int k0 = gi * 64;
        const bf16x8_t kv = *(const bf16x8_t*)(kgp + (size_t)(k0 + skey)*768);
        *(bf16x8_t*)(Kg + ((skey*64 + sc*16) ^ kswz)) = kv;
        const bf16x8_t vv = *(const bf16x8_t*)(vgp + k0);
        *(bf16x8_t*)(Vg + ((sd*128 + skc*16) ^ vswz)) = vv;
        mwc = *(const uint2*)(mrow + gi*2);
    }

    for (int i = 0; i < 32; ++i) {
        __syncthreads();
        const int cur = i & 1;
        const int tt = 2*i + gi;
        uint2 mwn;
        if (i < 31) {   // prefetch this group's next tile (tt+2) + its mask
            const int k0n = (tt + 2) * 64;
            const bf16x8_t kv = *(const bf16x8_t*)(kgp + (size_t)(k0n + skey)*768);
            *(bf16x8_t*)(Kg + (cur^1)*4096 + ((skey*64 + sc*16) ^ kswz)) = kv;
            const bf16x8_t vv = *(const bf16x8_t*)(vgp + k0n);
            *(bf16x8_t*)(Vg + (cur^1)*4096 + ((sd*128 + skc*16) ^ vswz)) = vv;
            mwn = *(const uint2*)(mrow + (tt + 2)*2);
        }
        char* Kb = Kg + cur*4096;
        char* Vb = Vg + cur*4096;

        // S^T = mfma(K, Q): col=q=ln, rows = keys kt*16+g*4+r
        f32x4_t s[4];
        __builtin_amdgcn_s_setprio(1);
        #pragma unroll
        for (int kt = 0; kt < 4; kt++) {
            const int key = kt*16 + ln;
            const bf16x8_t kf = *(const bf16x8_t*)(Kb + ((key*64 + g*16) ^ ((key & 7) << 4)));
            f32x4_t z = {0.f,0.f,0.f,0.f};
            s[kt] = __builtin_amdgcn_mfma_f32_16x16x32_bf16(kf, qf, z, 0, 0, 0);
        }
        __builtin_amdgcn_s_setprio(0);

        // fixed-shift masked exp2 (raw v_exp_f32); pack P -> LDS
        #pragma unroll
        for (int kt = 0; kt < 4; kt++) {
            const unsigned word = (kt < 2) ? mwc.x : mwc.y;
            float p[4];
            #pragma unroll
            for (int r = 0; r < 4; r++) {
                const float e = hw_exp2(s[kt][r] - 17.312340490667562f);  // 12*log2e
                p[r] = ((word >> ((kt & 1)*16 + g*4 + r)) & 1u) ? e : 0.f;
            }
            uint2 pk;
            pk.x = cvtpk_bf16(p[0], p[1]);
            pk.y = cvtpk_bf16(p[2], p[3]);
            *(uint2*)(Pw + ((ln*128 + kt*32 + g*8) ^ pswz)) = pk;
        }

        // PV: O^T += Vt . P ; lsum: oS += ones . P (matrix-pipe reduction)
        __builtin_amdgcn_s_setprio(1);
        #pragma unroll
        for (int kh = 0; kh < 2; kh++) {
            const bf16x8_t pf = *(const bf16x8_t*)(Pw + ((ln*128 + kh*64 + g*16) ^ pswz));
            const bf16x8_t vf0 = *(const bf16x8_t*)(Vb + ((ln*128 + kh*64 + g*16) ^ pswz));
            const bf16x8_t vf1 = *(const bf16x8_t*)(Vb + (((16+ln)*128 + kh*64 + g*16) ^ pswz));
            oT0 = __builtin_amdgcn_mfma_f32_16x16x32_bf16(vf0, pf, oT0, 0, 0, 0);
            oT1 = __builtin_amdgcn_mfma_f32_16x16x32_bf16(vf1, pf, oT1, 0, 0, 0);
            oS  = __builtin_amdgcn_mfma_f32_16x16x32_bf16(ones, pf, oS, 0, 0, 0);
        }
        __builtin_amdgcn_s_setprio(0);
        mwc = mwn;
    }

    // ---- additive merge of the two key-group partials ----
    // oS[0]: full sum over this group's keys for q=ln (identical across g).
    float lsum = oS[0];
    __syncthreads();
    *(f32x4_t*)(lds + w2*2048 + l*32)      = oT0;
    *(f32x4_t*)(lds + w2*2048 + l*32 + 16) = oT1;
    ((float*)(lds + 16384))[w2*64 + l] = lsum;
    __syncthreads();
    if (gi == 0) {
        const int pw = w2 + 4;
        const f32x4_t b0 = *(const f32x4_t*)(lds + pw*2048 + l*32);
        const f32x4_t b1 = *(const f32x4_t*)(lds + pw*2048 + l*32 + 16);
        const float lp = ((const float*)(lds + 16384))[pw*64 + l];
        oT0 += b0; oT1 += b1;
        lsum += lp;                       // no cross-lane reduce needed
        const float inv = 1.0f / fmaxf(lsum, 1e-37f);
        float* op = o + (size_t)qa * 256 + head*32;
        float4 v0 = {oT0[0]*inv, oT0[1]*inv, oT0[2]*inv, oT0[3]*inv};
        float4 v1 = {oT1[0]*inv, oT1[1]*inv, oT1[2]*inv, oT1[3]*inv};
        *(float4*)(op + g*4) = v0;
        *(float4*)(op + 16 + g*4) = v1;
    }
}

// ---------------------------------------------------------------------------
// LayerNorm over 256 dims, one block per row.
// ---------------------------------------------------------------------------
__global__ __launch_bounds__(256)
void ln_k(const float* __restrict__ in, const float* __restrict__ g,
          const float* __restrict__ b, float* __restrict__ out)
{
    const int n = blockIdx.x, t = threadIdx.x;
    const float v = in[(size_t)n * 256 + t];
    float s1 = v, s2 = v * v;
    #pragma unroll
    for (int off = 32; off > 0; off >>= 1) {
        s1 += __shfl_xor(s1, off);
        s2 += __shfl_xor(s2, off);
    }
    __shared__ float r1[4], r2[4];
    const int wv = t >> 6;
    if ((t & 63) == 0) { r1[wv] = s1; r2[wv] = s2; }
    __syncthreads();
    const float t1 = r1[0] + r1[1] + r1[2] + r1[3];
    const float t2 = r2[0] + r2[1] + r2[2] + r2[3];
    const float mu  = t1 * (1.0f / 256.0f);
    const float var = t2 * (1.0f / 256.0f) - mu * mu;
    const float rs  = rsqrtf(var + 1e-5f);
    out[(size_t)n * 256 + t] = (v - mu) * rs * g[t] + b[t];
}

// ---------------------------------------------------------------------------
extern "C" void kernel_launch(void* const* d_in, const int* in_sizes, int n_in,
                              void* d_out, int out_size, void* d_ws, size_t ws_size,
                              hipStream_t stream)
{
    const float* x     = (const float*)d_in[0];
    const int*   ei    = (const int*)  d_in[1];
    const float* eattr = (const float*)d_in[2];
    const int*   mask  = (const int*)  d_in[3];
    const float* W1   = (const float*)d_in[4];
    const float* b1   = (const float*)d_in[5];
    const float* W2   = (const float*)d_in[6];
    const float* b2   = (const float*)d_in[7];
    const float* ipw  = (const float*)d_in[8];
    const float* ipb  = (const float*)d_in[9];
    const float* ow   = (const float*)d_in[10];
    const float* ob   = (const float*)d_in[11];
    const float* root = (const float*)d_in[12];
    const float* bp   = (const float*)d_in[13];
    const float* ln1g = (const float*)d_in[14];
    const float* ln1b = (const float*)d_in[15];
    const float* ln2g = (const float*)d_in[16];
    const float* ln2b = (const float*)d_in[17];
    const float* linw = (const float*)d_in[18];
    const float* linb = (const float*)d_in[19];
    const int* ei0 = ei;
    const int* ei1 = ei + E_;

    float* ws = (float*)d_ws;
    short* h1b   = (short*)ws;                      // [E,256] bf16
    short* hb    = (short*)(ws + 524288);           // [E,256] bf16
    float* o     = ws + 1048576;                    // [E,256] f32 (attn out)
    float* y1    = ws + 1048576;                    //   reuse: o dead after S5
    float* z     = ws + 1572864;                    //   reuse: o dead after S5
    short* qkvb  = (short*)(ws + 2097152);          // [E,768] bf16 (q pre-scaled)
    float* aggr  = ws + 3670016;                    // [N,256] f32
    float* outb  = ws + 4194304;                    // [N,256] f32
    unsigned int* pmask = (unsigned int*)(ws + 4718592);  // [4096][128] bits
    short* vt    = (short*)(ws + 5242896);          // [8][32][4096] bf16
    float* rootT = ws + 5767184;                    // [256][256] f32

    dim3 blk(256);
    dim3 blk512(512);
    // prep: mask bits + aggr zero + rootT
    prep_k<<<dim3(2064), blk, 0, stream>>>(mask, pmask, root, rootT, aggr);

    // S1: h1b = bf16(leakyrelu(cat(x_i,x_j,eattr) @ W1^T + b1))   [MFMA]
    mgemm_k<64,1,true,false,false,false,1><<<dim3(64,4), blk512, 0, stream>>>(
        nullptr, W1, b1, nullptr, h1b, nullptr, E_, 256, 768, ei0, ei1, x, eattr, 1.0f);
    // S2: hb = bf16(h1b @ W2^T + b2)   [MFMA, bf16 A]
    mgemm_k<64,0,false,false,false,true,1><<<dim3(64,4), blk512, 0, stream>>>(
        h1b, W2, b2, nullptr, hb, nullptr, E_, 256, 256, nullptr, nullptr, nullptr, nullptr, 1.0f);
    // S3: qkvb + vt = hb @ in_proj_w^T + b; q scaled by log2e/sqrt(32);
    //     V columns written transposed into vt (vtrans folded in)
    mgemm_k<64,0,false,false,false,true,2><<<dim3(64,12), blk512, 0, stream>>>(
        hb, ipw, ipb, nullptr, qkvb, vt, E_, 768, 256, nullptr, nullptr, nullptr, nullptr,
        0.25503486f);   // log2(e)/sqrt(32)
    // S4: MFMA flash attention -> o (f32)
    attn_k<<<dim3(512), dim3(512), 0, stream>>>(qkvb, vt, pmask, o);
    // S5: msg = o @ out_w^T + out_b, scatter-add to aggr   [MFMA]
    mgemm_k<64,0,false,true,false,false,0><<<dim3(64,4), blk512, 0, stream>>>(
        o, ow, ob, nullptr, aggr, nullptr, E_, 256, 256, nullptr, ei1, nullptr, nullptr, 1.0f);
    // S6: outb = x @ root + aggr + bias_p   [MFMA BM=32 + exact f32 add]
    mgemm_k<32,0,false,false,true,false,0><<<dim3(64,4), blk512, 0, stream>>>(
        x, rootT, bp, aggr, outb, nullptr, NN_, 256, 256, nullptr, nullptr, nullptr, nullptr, 1.0f);
    // LN1
    ln_k<<<dim3(2048), blk, 0, stream>>>(outb, ln1g, ln1b, y1);
    // F2: z = y1 + y1 @ lin_w^T + lin_b   [MFMA BM=32 + exact f32 residual]
    mgemm_k<32,0,false,false,true,false,0><<<dim3(64,4), blk512, 0, stream>>>(
        y1, linw, linb, y1, z, nullptr, NN_, 256, 256, nullptr, nullptr, nullptr, nullptr, 1.0f);
    // LN2 -> out
    ln_k<<<dim3(2048), blk, 0, stream>>>(z, ln2g, ln2b, (float*)d_out);
}

// Round 18
// 103.876 us; speedup vs baseline: 1.3247x; 1.0510x over previous
//
#include <hip/hip_runtime.h>
#include <hip/hip_bf16.h>
#include <cstdint>

#define D_   256
#define E_   4096
#define NN_  2048

typedef float f32x4_t __attribute__((ext_vector_type(4)));
typedef short bf16x8_t __attribute__((ext_vector_type(8)));
typedef short bf16x4_t __attribute__((ext_vector_type(4)));

__device__ inline short f2bf(float f) {
    union { float fv; unsigned u; } v; v.fv = f;
    unsigned r = v.u + 0x7fffu + ((v.u >> 16) & 1u);
    return (short)(r >> 16);
}

__device__ inline unsigned cvtpk_bf16(float lo, float hi) {
    unsigned r;
    asm("v_cvt_pk_bf16_f32 %0, %1, %2" : "=v"(r) : "v"(lo), "v"(hi));
    return r;
}

// Raw hardware exp2: v_exp_f32 computes 2^x in one transcendental op.
// (exp2f() is the PRECISE OCML call — cost ~15us/attn, r13 lesson.)
__device__ inline float hw_exp2(float x) {
    float r;
    asm("v_exp_f32 %0, %1" : "=v"(r) : "v"(x));
    return r;
}

// bf16 weight buffer layout (elements):
//   wb1 @0 (768x256), wb2 @196608 (256x256), wipw @262144 (768x256),
//   wow @458752 (256x256), wlin @524288 (256x256), wrootT @589824 (256x256)
#define WB1   0
#define WB2   196608
#define WIPW  262144
#define WOW   458752
#define WLIN  524288
#define WROOT 589824

// ---------------------------------------------------------------------------
// bf16 MFMA GEMM, BK=64, 8 waves, BM in {64,32} (r17/r18).
// B is PRE-CONVERTED bf16 (r18): one 16B load/thread/step, no cvt_pk.
// BM=64: wave = 16x32 (2 frags). BM=32: wave = 16x16 (1 frag) — for M=2048
// stages (2x blocks beats bigger tiles when latency-bound).
// ABF16: A bf16. OUT: 0=f32, 1=bf16 (cols<256 scaled by qsc), 2=qkv split.
// SCATTER: f32 atomicAdd via ei1. HASADD: += addsrc (f32, exact).
// ---------------------------------------------------------------------------
template<int BM, int ACT, bool GATHER, bool SCATTER, bool HASADD, bool ABF16, int OUT>
__global__ __launch_bounds__(512)
void mgemm_k(const void* __restrict__ A, const short* __restrict__ Bmb,
             const float* __restrict__ bias, const float* __restrict__ addsrc,
             void* __restrict__ C, short* __restrict__ vtb,
             int M, int N, int K,
             const int* __restrict__ ei0, const int* __restrict__ ei1,
             const float* __restrict__ x, const float* __restrict__ eattr,
             float qsc)
{
    constexpr int ASZ  = BM * 128;
    constexpr int BOFF = 2 * ASZ;
    constexpr int NFR  = (BM == 64) ? 2 : 1;
    __shared__ char lds[BOFF + 16384];
    const int tid = threadIdx.x;
    const int w = tid >> 6, l = tid & 63;
    const int g = l >> 4, ln = l & 15;
    const int wr = (BM == 64) ? (w >> 1) : (w >> 2);
    const int wc = (BM == 64) ? (w & 1)  : (w & 3);
    const int m0 = blockIdx.x * BM, n0 = blockIdx.y * 64;

    const int srow = tid >> 3;
    const int sck  = (tid & 7) * 8;
    const int sswz = (srow & 7) << 4;
    const bool doA = (BM == 64) || (tid < 256);
    int gi1 = 0, gi0 = 0;
    if (GATHER) { gi1 = ei1[m0 + srow]; gi0 = ei0[m0 + srow]; }

    f32x4_t acc[NFR];
    #pragma unroll
    for (int n = 0; n < NFR; n++) acc[n] = f32x4_t{0.f,0.f,0.f,0.f};

    const int nt = K >> 6;
    float4 ga[2];
    bf16x8_t gab, gbb;

    auto loadG = [&](int kk) {
        const int cb = kk + sck;
        if (doA) {
            if (ABF16) {
                gab = *(const bf16x8_t*)((const short*)A + (size_t)(m0 + srow) * K + cb);
            } else {
                const float* src;
                if (GATHER) {
                    if (cb < 256)      src = x + (size_t)gi1 * 256 + cb;
                    else if (cb < 512) src = x + (size_t)gi0 * 256 + (cb - 256);
                    else               src = eattr + (size_t)(m0 + srow) * 256 + (cb - 512);
                } else {
                    src = (const float*)A + (size_t)(m0 + srow) * K + cb;
                }
                ga[0] = *(const float4*)src;
                ga[1] = *(const float4*)(src + 4);
            }
        }
        gbb = *(const bf16x8_t*)(Bmb + (size_t)(n0 + srow) * K + cb);
    };
    auto writeS = [&](int buf) {
        const int off = (srow*128 + sck*2) ^ sswz;
        if (doA) {
            if (ABF16) {
                *(bf16x8_t*)(lds + buf*ASZ + off) = gab;
            } else {
                uint4 pa;
                pa.x = cvtpk_bf16(ga[0].x, ga[0].y); pa.y = cvtpk_bf16(ga[0].z, ga[0].w);
                pa.z = cvtpk_bf16(ga[1].x, ga[1].y); pa.w = cvtpk_bf16(ga[1].z, ga[1].w);
                *(uint4*)(lds + buf*ASZ + off) = pa;
            }
        }
        *(bf16x8_t*)(lds + BOFF + buf*8192 + off) = gbb;
    };

    loadG(0);
    writeS(0);
    __syncthreads();
    int cur = 0;
    for (int t = 0; t < nt; ++t) {
        if (t + 1 < nt) loadG((t + 1) << 6);
        #pragma unroll
        for (int kc = 0; kc < 2; kc++) {
            const int arow = wr*16 + ln;
            const bf16x8_t af = *(const bf16x8_t*)(lds + cur*ASZ +
                    ((arow*128 + kc*64 + g*16) ^ ((arow&7)<<4)));
            #pragma unroll
            for (int n = 0; n < NFR; n++) {
                const int brow = (BM == 64 ? wc*32 + n*16 : wc*16) + ln;
                const bf16x8_t bfr = *(const bf16x8_t*)(lds + BOFF + cur*8192 +
                         ((brow*128 + kc*64 + g*16) ^ ((brow&7)<<4)));
                acc[n] = __builtin_amdgcn_mfma_f32_16x16x32_bf16(af, bfr, acc[n], 0, 0, 0);
            }
        }
        if (t + 1 < nt) writeS(cur ^ 1);
        __syncthreads();
        cur ^= 1;
    }

    #pragma unroll
    for (int n = 0; n < NFR; n++) {
        const int col = n0 + (BM == 64 ? wc*32 + n*16 : wc*16) + ln;
        const float bv = bias[col];
        const int row0 = m0 + wr*16 + g*4;
        float pv[4];
        #pragma unroll
        for (int r = 0; r < 4; r++) {
            float v = acc[n][r] + bv;
            if (ACT == 1) v = v > 0.f ? v : 0.2f * v;
            if (HASADD) v += addsrc[(size_t)(row0 + r) * N + col];
            pv[r] = v;
        }
        if (SCATTER) {
            #pragma unroll
            for (int r = 0; r < 4; r++)
                atomicAdd(&((float*)C)[(size_t)ei1[row0 + r] * 256 + col], pv[r]);
        } else if (OUT == 0) {
            #pragma unroll
            for (int r = 0; r < 4; r++)
                ((float*)C)[(size_t)(row0 + r) * N + col] = pv[r];
        } else if (OUT == 1) {
            #pragma unroll
            for (int r = 0; r < 4; r++)
                ((short*)C)[(size_t)(row0 + r) * N + col] =
                    f2bf((col < 256) ? pv[r] * qsc : pv[r]);
        } else {   // OUT == 2: qkv split
            if (col < 512) {
                #pragma unroll
                for (int r = 0; r < 4; r++)
                    ((short*)C)[(size_t)(row0 + r) * 768 + col] =
                        f2bf((col < 256) ? pv[r] * qsc : pv[r]);
            } else {
                const int hd = (col - 512) >> 5, d = (col - 512) & 31;
                bf16x4_t pk;
                #pragma unroll
                for (int r = 0; r < 4; r++) pk[r] = f2bf(pv[r]);
                *(bf16x4_t*)(vtb + (size_t)hd*131072 + (size_t)d*4096 + row0) = pk;
            }
        }
    }
}

// ---------------------------------------------------------------------------
// Prep (r18): mask bit-pack + aggr zero (blocks 0..2047); rootT transpose to
// bf16 (2048..2063); weight f32->bf16 conversion (2064..2351, RNE cvt_pk —
// bit-identical to the per-step conversion it replaces).
// ---------------------------------------------------------------------------
__global__ __launch_bounds__(256)
void prep_k(const int* __restrict__ mraw, unsigned int* __restrict__ pm,
            const float* __restrict__ root,
            const float* __restrict__ W1, const float* __restrict__ W2,
            const float* __restrict__ ipw, const float* __restrict__ ow,
            const float* __restrict__ lnw,
            short* __restrict__ wbuf, float* __restrict__ aggr)
{
    __shared__ float T[64][65];
    const int bid = blockIdx.x;
    if (bid < 2048) {
        const int t = bid * 256 + threadIdx.x;
        aggr[t] = 0.f;
        const int row = t >> 7, wb = t & 127;
        unsigned int bits = 0;
        const uint4* p = (const uint4*)(mraw + (size_t)row * 4096 + wb * 32);
        #pragma unroll
        for (int g = 0; g < 8; g++) {
            const uint4 v = p[g];
            if (v.x) bits |= 1u << (g*4+0);
            if (v.y) bits |= 1u << (g*4+1);
            if (v.z) bits |= 1u << (g*4+2);
            if (v.w) bits |= 1u << (g*4+3);
        }
        pm[t] = bits;
    } else if (bid < 2064) {
        const int bt = bid - 2048;
        const int m0 = (bt >> 2) * 64, n0 = (bt & 3) * 64;
        const int r = threadIdx.x >> 6, c = threadIdx.x & 63;
        #pragma unroll
        for (int i = 0; i < 16; i++)
            T[r + i*4][c] = root[(size_t)(m0 + r + i*4) * 256 + n0 + c];
        __syncthreads();
        #pragma unroll
        for (int i = 0; i < 16; i++)
            wbuf[WROOT + (size_t)(n0 + r + i*4) * 256 + m0 + c] = f2bf(T[c][r + i*4]);
    } else {
        const int wid = bid - 2064;        // 0..287
        const float* src; int dst, lw;
        if (wid < 96)       { src = W1;  dst = WB1;  lw = wid; }
        else if (wid < 128) { src = W2;  dst = WB2;  lw = wid - 96; }
        else if (wid < 224) { src = ipw; dst = WIPW; lw = wid - 128; }
        else if (wid < 256) { src = ow;  dst = WOW;  lw = wid - 224; }
        else                { src = lnw; dst = WLIN; lw = wid - 256; }
        const int e0 = (lw * 256 + threadIdx.x) * 8;
        const float4 a = *(const float4*)(src + e0);
        const float4 b = *(const float4*)(src + e0 + 4);
        uint4 p;
        p.x = cvtpk_bf16(a.x, a.y); p.y = cvtpk_bf16(a.z, a.w);
        p.z = cvtpk_bf16(b.x, b.y); p.w = cvtpk_bf16(b.z, b.w);
        *(uint4*)(wbuf + dst + e0) = p;
    }
}

// ---------------------------------------------------------------------------
// MFMA bf16 flash attention (r17 structure; r18: o written as bf16 — S5
// rounds A to bf16 during staging anyway, so numerics are identical).
// Swapped QK^T; fixed-shift base-2 softmax (q pre-scaled by log2e/sqrt(32),
// p = hw_exp2(s - 12*log2e)); split-K x2 strided; dbuf K/V; setprio; mask
// prefetch; lsum via ones-MFMA; additive merge.
// DO NOT widen split-K (r9/r5 L2 collapse); exp2f is OCML (r13).
// ---------------------------------------------------------------------------
__global__ __launch_bounds__(512, 4)
void attn_k(const short* __restrict__ qkvb, const short* __restrict__ vt,
            const unsigned int* __restrict__ pmask, short* __restrict__ ob)
{
    __shared__ char lds[49152];
    const int tid = threadIdx.x;
    const int w2 = tid >> 6, l = tid & 63;
    const int g = l >> 4, ln = l & 15;
    const int gi = w2 >> 2, wq = w2 & 3;
    const int head = blockIdx.x >> 6;
    const int q0 = (blockIdx.x & 63) * 64;
    const int qa = q0 + wq * 16 + ln;

    const bf16x8_t qf = *(const bf16x8_t*)(qkvb + (size_t)qa*768 + head*32 + g*8);
    bf16x8_t ones;
    #pragma unroll
    for (int j = 0; j < 8; j++) ones[j] = (short)0x3F80;   // bf16 1.0

    f32x4_t oT0 = {0.f,0.f,0.f,0.f};
    f32x4_t oT1 = {0.f,0.f,0.f,0.f};
    f32x4_t oS  = {0.f,0.f,0.f,0.f};

    const int st = tid & 255;
    const int skey = st >> 2, sc = st & 3;
    const int sd = st >> 3, skc = st & 7;
    const short* kgp = qkvb + 256 + head*32 + sc*8;
    const short* vgp = vt + (size_t)head*131072 + (size_t)sd*4096 + skc*8;
    char* Kg = lds + gi*8192;
    char* Vg = lds + 16384 + gi*8192;
    char* Pw = lds + 32768 + w2*2048;
    const unsigned int* mrow = pmask + (size_t)qa*128;
    const int kswz = (skey & 7) << 4, vswz = (sd & 7) << 4;
    const int pswz = (ln & 7) << 4;

    uint2 mwc;
    {
        const int k0 = gi * 64;
        const bf16x8_t kv = *(const bf16x8_t*)(kgp + (size_t)(k0 + skey)*768);
        *(bf16x8_t*)(Kg + ((skey*64 + sc*16) ^ kswz)) = kv;
        const bf16x8_t vv = *(const bf16x8_t*)(vgp + k0);
        *(bf16x8_t*)(Vg + ((sd*128 + skc*16) ^ vswz)) = vv;
        mwc = *(const uint2*)(mrow + gi*2);
    }

    for (int i = 0; i < 32; ++i) {
        __syncthreads();
        const int cur = i & 1;
        const int tt = 2*i + gi;
        uint2 mwn;
        if (i < 31) {
            const int k0n = (tt + 2) * 64;
            const bf16x8_t kv = *(const bf16x8_t*)(kgp + (size_t)(k0n + skey)*768);
            *(bf16x8_t*)(Kg + (cur^1)*4096 + ((skey*64 + sc*16) ^ kswz)) = kv;
            const bf16x8_t vv = *(const bf16x8_t*)(vgp + k0n);
            *(bf16x8_t*)(Vg + (cur^1)*4096 + ((sd*128 + skc*16) ^ vswz)) = vv;
            mwn = *(const uint2*)(mrow + (tt + 2)*2);
        }
        char* Kb = Kg + cur*4096;
        char* Vb = Vg + cur*4096;

        f32x4_t s[4];
        __builtin_amdgcn_s_setprio(1);
        #pragma unroll
        for (int kt = 0; kt < 4; kt++) {
            const int key = kt*16 + ln;
            const bf16x8_t kf = *(const bf16x8_t*)(Kb + ((key*64 + g*16) ^ ((key & 7) << 4)));
            f32x4_t z = {0.f,0.f,0.f,0.f};
            s[kt] = __builtin_amdgcn_mfma_f32_16x16x32_bf16(kf, qf, z, 0, 0, 0);
        }
        __builtin_amdgcn_s_setprio(0);

        #pragma unroll
        for (int kt = 0; kt < 4; kt++) {
            const unsigned word = (kt < 2) ? mwc.x : mwc.y;
            float p[4];
            #pragma unroll
            for (int r = 0; r < 4; r++) {
                const float e = hw_exp2(s[kt][r] - 17.312340490667562f);  // 12*log2e
                p[r] = ((word >> ((kt & 1)*16 + g*4 + r)) & 1u) ? e : 0.f;
            }
            uint2 pk;
            pk.x = cvtpk_bf16(p[0], p[1]);
            pk.y = cvtpk_bf16(p[2], p[3]);
            *(uint2*)(Pw + ((ln*128 + kt*32 + g*8) ^ pswz)) = pk;
        }

        __builtin_amdgcn_s_setprio(1);
        #pragma unroll
        for (int kh = 0; kh < 2; kh++) {
            const bf16x8_t pf = *(const bf16x8_t*)(Pw + ((ln*128 + kh*64 + g*16) ^ pswz));
            const bf16x8_t vf0 = *(const bf16x8_t*)(Vb + ((ln*128 + kh*64 + g*16) ^ pswz));
            const bf16x8_t vf1 = *(const bf16x8_t*)(Vb + (((16+ln)*128 + kh*64 + g*16) ^ pswz));
            oT0 = __builtin_amdgcn_mfma_f32_16x16x32_bf16(vf0, pf, oT0, 0, 0, 0);
            oT1 = __builtin_amdgcn_mfma_f32_16x16x32_bf16(vf1, pf, oT1, 0, 0, 0);
            oS  = __builtin_amdgcn_mfma_f32_16x16x32_bf16(ones, pf, oS, 0, 0, 0);
        }
        __builtin_amdgcn_s_setprio(0);
        mwc = mwn;
    }

    float lsum = oS[0];
    __syncthreads();
    *(f32x4_t*)(lds + w2*2048 + l*32)      = oT0;
    *(f32x4_t*)(lds + w2*2048 + l*32 + 16) = oT1;
    ((float*)(lds + 16384))[w2*64 + l] = lsum;
    __syncthreads();
    if (gi == 0) {
        const int pw = w2 + 4;
        const f32x4_t b0 = *(const f32x4_t*)(lds + pw*2048 + l*32);
        const f32x4_t b1 = *(const f32x4_t*)(lds + pw*2048 + l*32 + 16);
        const float lp = ((const float*)(lds + 16384))[pw*64 + l];
        oT0 += b0; oT1 += b1;
        lsum += lp;
        const float inv = 1.0f / fmaxf(lsum, 1e-37f);
        short* op = ob + (size_t)qa * 256 + head*32;
        uint2 w0, w1;
        w0.x = cvtpk_bf16(oT0[0]*inv, oT0[1]*inv);
        w0.y = cvtpk_bf16(oT0[2]*inv, oT0[3]*inv);
        w1.x = cvtpk_bf16(oT1[0]*inv, oT1[1]*inv);
        w1.y = cvtpk_bf16(oT1[2]*inv, oT1[3]*inv);
        *(uint2*)(op + g*4) = w0;
        *(uint2*)(op + 16 + g*4) = w1;
    }
}

// ---------------------------------------------------------------------------
// LayerNorm over 256 dims, one block per row.
// ---------------------------------------------------------------------------
__global__ __launch_bounds__(256)
void ln_k(const float* __restrict__ in, const float* __restrict__ g,
          const float* __restrict__ b, float* __restrict__ out)
{
    const int n = blockIdx.x, t = threadIdx.x;
    const float v = in[(size_t)n * 256 + t];
    float s1 = v, s2 = v * v;
    #pragma unroll
    for (int off = 32; off > 0; off >>= 1) {
        s1 += __shfl_xor(s1, off);
        s2 += __shfl_xor(s2, off);
    }
    __shared__ float r1[4], r2[4];
    const int wv = t >> 6;
    if ((t & 63) == 0) { r1[wv] = s1; r2[wv] = s2; }
    __syncthreads();
    const float t1 = r1[0] + r1[1] + r1[2] + r1[3];
    const float t2 = r2[0] + r2[1] + r2[2] + r2[3];
    const float mu  = t1 * (1.0f / 256.0f);
    const float var = t2 * (1.0f / 256.0f) - mu * mu;
    const float rs  = rsqrtf(var + 1e-5f);
    out[(size_t)n * 256 + t] = (v - mu) * rs * g[t] + b[t];
}

// ---------------------------------------------------------------------------
extern "C" void kernel_launch(void* const* d_in, const int* in_sizes, int n_in,
                              void* d_out, int out_size, void* d_ws, size_t ws_size,
                              hipStream_t stream)
{
    const float* x     = (const float*)d_in[0];
    const int*   ei    = (const int*)  d_in[1];
    const float* eattr = (const float*)d_in[2];
    const int*   mask  = (const int*)  d_in[3];
    const float* W1   = (const float*)d_in[4];
    const float* b1   = (const float*)d_in[5];
    const float* W2   = (const float*)d_in[6];
    const float* b2   = (const float*)d_in[7];
    const float* ipw  = (const float*)d_in[8];
    const float* ipb  = (const float*)d_in[9];
    const float* ow   = (const float*)d_in[10];
    const float* ob_  = (const float*)d_in[11];
    const float* root = (const float*)d_in[12];
    const float* bp   = (const float*)d_in[13];
    const float* ln1g = (const float*)d_in[14];
    const float* ln1b = (const float*)d_in[15];
    const float* ln2g = (const float*)d_in[16];
    const float* ln2b = (const float*)d_in[17];
    const float* linw = (const float*)d_in[18];
    const float* linb = (const float*)d_in[19];
    const int* ei0 = ei;
    const int* ei1 = ei + E_;

    float* ws = (float*)d_ws;
    short* h1b   = (short*)ws;                      // [E,256] bf16
    short* hb    = (short*)(ws + 524288);           // [E,256] bf16
    short* o     = (short*)(ws + 1048576);          // [E,256] bf16 (attn out)
    float* y1    = ws + 1048576;                    //   reuse: o dead after S5
    float* z     = ws + 1572864;                    //   reuse: o dead after S5
    short* qkvb  = (short*)(ws + 2097152);          // [E,768] bf16 (q pre-scaled)
    float* aggr  = ws + 3670016;                    // [N,256] f32
    float* outb  = ws + 4194304;                    // [N,256] f32
    unsigned int* pmask = (unsigned int*)(ws + 4718592);  // [4096][128] bits
    short* vt    = (short*)(ws + 5242896);          // [8][32][4096] bf16
    short* wbuf  = (short*)(ws + 5767184);          // bf16 weights, 655360 el

    dim3 blk(256);
    dim3 blk512(512);
    // prep: mask bits + aggr zero + rootT(bf16) + weight f32->bf16
    prep_k<<<dim3(2352), blk, 0, stream>>>(mask, pmask, root, W1, W2, ipw, ow,
                                           linw, wbuf, aggr);

    // S1: h1b = bf16(leakyrelu(cat(x_i,x_j,eattr) @ W1^T + b1))   [MFMA]
    mgemm_k<64,1,true,false,false,false,1><<<dim3(64,4), blk512, 0, stream>>>(
        nullptr, wbuf + WB1, b1, nullptr, h1b, nullptr, E_, 256, 768, ei0, ei1, x, eattr, 1.0f);
    // S2: hb = bf16(h1b @ W2^T + b2)   [MFMA, bf16 A+B]
    mgemm_k<64,0,false,false,false,true,1><<<dim3(64,4), blk512, 0, stream>>>(
        h1b, wbuf + WB2, b2, nullptr, hb, nullptr, E_, 256, 256, nullptr, nullptr, nullptr, nullptr, 1.0f);
    // S3: qkvb + vt = hb @ in_proj_w^T + b; q scaled by log2e/sqrt(32);
    //     V columns written transposed into vt
    mgemm_k<64,0,false,false,false,true,2><<<dim3(64,12), blk512, 0, stream>>>(
        hb, wbuf + WIPW, ipb, nullptr, qkvb, vt, E_, 768, 256, nullptr, nullptr, nullptr, nullptr,
        0.25503486f);   // log2(e)/sqrt(32)
    // S4: MFMA flash attention -> o (bf16)
    attn_k<<<dim3(512), dim3(512), 0, stream>>>(qkvb, vt, pmask, o);
    // S5: msg = o @ out_w^T + out_b, scatter-add to aggr   [MFMA, bf16 A+B]
    mgemm_k<64,0,false,true,false,true,0><<<dim3(64,4), blk512, 0, stream>>>(
        o, wbuf + WOW, ob_, nullptr, aggr, nullptr, E_, 256, 256, nullptr, ei1, nullptr, nullptr, 1.0f);
    // S6: outb = x @ root + aggr + bias_p   [MFMA BM=32 + exact f32 add]
    mgemm_k<32,0,false,false,true,false,0><<<dim3(64,4), blk512, 0, stream>>>(
        x, wbuf + WROOT, bp, aggr, outb, nullptr, NN_, 256, 256, nullptr, nullptr, nullptr, nullptr, 1.0f);
    // LN1
    ln_k<<<dim3(2048), blk, 0, stream>>>(outb, ln1g, ln1b, y1);
    // F2: z = y1 + y1 @ lin_w^T + lin_b   [MFMA BM=32 + exact f32 residual]
    mgemm_k<32,0,false,false,true,false,0><<<dim3(64,4), blk512, 0, stream>>>(
        y1, wbuf + WLIN, linb, y1, z, nullptr, NN_, 256, 256, nullptr, nullptr, nullptr, nullptr, 1.0f);
    // LN2 -> out
    ln_k<<<dim3(2048), blk, 0, stream>>>(z, ln2g, ln2b, (float*)d_out);
}